// Round 8
// baseline (517.480 us; speedup 1.0000x reference)
//
#include <hip/hip_runtime.h>
#include <hip/hip_bf16.h>

constexpr int Bb = 2, Nn = 2048, Ff = 768, Hh = 8, Oo = 256;

typedef __attribute__((ext_vector_type(8)))  short   short8;
typedef __attribute__((ext_vector_type(16))) float   f32x16;
typedef __attribute__((ext_vector_type(4)))  unsigned short ushort4_t;

__device__ inline unsigned short f2bf(float f) {
    unsigned u = __float_as_uint(f);
    u = (u + 0x7FFFu + ((u >> 16) & 1u)) >> 16;   // RNE
    return (unsigned short)u;
}

// ---------------- adjacency bitmask ----------------
__global__ __launch_bounds__(256) void adjbits_kernel(
        const float* __restrict__ adj, unsigned long long* __restrict__ bits) {
    size_t gid = (size_t)blockIdx.x * 256 + threadIdx.x;
    float v = adj[gid];
    unsigned long long m = __ballot(v > 0.f);
    if ((threadIdx.x & 63) == 0) bits[gid >> 6] = m;
}

// ---------------- f32 -> bf16 flat cast ----------------
__global__ __launch_bounds__(256) void cast_bf_kernel(
        const float* __restrict__ in, unsigned short* __restrict__ out) {
    size_t i = (size_t)blockIdx.x * 256 + threadIdx.x;
    float4 v = ((const float4*)in)[i];
    ushort4_t o;
    o.x = f2bf(v.x); o.y = f2bf(v.y); o.z = f2bf(v.z); o.w = f2bf(v.w);
    ((ushort4_t*)out)[i] = o;
}

// ---------------- [z][R][C] f32 -> [z][C][R] bf16 transpose ----------------
__global__ __launch_bounds__(256) void transpose_bf_kernel(
        const float* __restrict__ in, unsigned short* __restrict__ out, int R, int C) {
    __shared__ float tile[32][33];
    int c0 = blockIdx.x * 32, r0 = blockIdx.y * 32;
    const float* ib = in + (size_t)blockIdx.z * R * C;
    unsigned short* ob = out + (size_t)blockIdx.z * R * C;
    int tx = threadIdx.x & 31, ty = threadIdx.x >> 5;
    for (int k = 0; k < 32; k += 8)
        tile[ty + k][tx] = ib[(size_t)(r0 + ty + k) * C + c0 + tx];
    __syncthreads();
    for (int k = 0; k < 32; k += 8)
        ob[(size_t)(c0 + ty + k) * R + r0 + tx] = f2bf(tile[tx][ty + k]);
}

// ---------------- MFMA GEMM: C[M x 256] = A[M x K] * BT[256 x K]^T ----------------
__global__ __launch_bounds__(256) void gemm_bf_kernel(
        const unsigned short* __restrict__ A, int K, long long sA, int bAshift,
        const unsigned short* __restrict__ BT, long long sB, int bmask,
        float* __restrict__ C, long long sC,
        unsigned short* __restrict__ CT, long long sCT, int Mtot,
        const float* __restrict__ bias, int mode) {
    int z = blockIdx.z;
    A  += (size_t)(z >> bAshift) * sA;
    BT += (size_t)(z & bmask) * sB;
    C  += (size_t)z * sC;
    if (CT) CT += (size_t)z * sCT;
    int m0 = blockIdx.x * 64;
    int t = threadIdx.x;
    int wv = t >> 6, lane = t & 63;
    int lm = lane & 31, kh = lane >> 5;
    __shared__ unsigned short As[64][40];
    f32x16 acc[2][2] = {};
    int sr = t >> 2, sc = (t & 3) * 8;
    const unsigned short* ag  = A + (size_t)(m0 + sr) * K + sc;
    const unsigned short* bg0 = BT + (size_t)(wv * 64 + lm) * K;
    const unsigned short* bg1 = BT + (size_t)(wv * 64 + 32 + lm) * K;
    for (int k0 = 0; k0 < K; k0 += 32) {
        *(short8*)&As[sr][sc] = *(const short8*)(ag + k0);
        __syncthreads();
#pragma unroll
        for (int ks = 0; ks < 32; ks += 16) {
            short8 a0 = *(const short8*)&As[lm][ks + kh * 8];
            short8 a1 = *(const short8*)&As[32 + lm][ks + kh * 8];
            short8 b0 = *(const short8*)(bg0 + k0 + ks + kh * 8);
            short8 b1 = *(const short8*)(bg1 + k0 + ks + kh * 8);
            acc[0][0] = __builtin_amdgcn_mfma_f32_32x32x16_bf16(a0, b0, acc[0][0], 0, 0, 0);
            acc[0][1] = __builtin_amdgcn_mfma_f32_32x32x16_bf16(a0, b1, acc[0][1], 0, 0, 0);
            acc[1][0] = __builtin_amdgcn_mfma_f32_32x32x16_bf16(a1, b0, acc[1][0], 0, 0, 0);
            acc[1][1] = __builtin_amdgcn_mfma_f32_32x32x16_bf16(a1, b1, acc[1][1], 0, 0, 0);
        }
        __syncthreads();
    }
#pragma unroll
    for (int mt = 0; mt < 2; ++mt)
#pragma unroll
        for (int nt = 0; nt < 2; ++nt) {
            int colg = wv * 64 + nt * 32 + lm;
            float bv = (mode == 2) ? bias[colg] : 0.f;
#pragma unroll
            for (int reg = 0; reg < 16; ++reg) {
                int rl = mt * 32 + 4 * kh + (reg & 3) + 8 * (reg >> 2);
                float v = acc[mt][nt][reg];
                if (mode == 2) { v += bv; v = fmaxf(v, 0.f); }
                C[(size_t)(m0 + rl) * 256 + colg] = v;
            }
            if (mode == 1) {
                unsigned short* ctp = CT + (size_t)colg * Mtot + m0 + mt * 32 + 4 * kh;
#pragma unroll
                for (int q = 0; q < 4; ++q) {
                    ushort4_t pk;
                    pk.x = f2bf(acc[mt][nt][q * 4 + 0]);
                    pk.y = f2bf(acc[mt][nt][q * 4 + 1]);
                    pk.z = f2bf(acc[mt][nt][q * 4 + 2]);
                    pk.w = f2bf(acc[mt][nt][q * 4 + 3]);
                    *(ushort4_t*)(ctp + 8 * q) = pk;
                }
            }
        }
}

// ---------------- dual MFMA GEMM: x1 @ [WoT ; Wl]^T in one launch ----------------
__global__ __launch_bounds__(256) void gemm_dual_kernel(
        const unsigned short* __restrict__ A, int K, long long sA,
        const unsigned short* __restrict__ BT,
        float* __restrict__ h2, unsigned short* __restrict__ h2T,
        float* __restrict__ lin) {
    int b = blockIdx.z, ng = blockIdx.y;
    A += (size_t)b * sA;
    BT += (size_t)ng * 256 * K;
    int m0 = blockIdx.x * 64;
    int t = threadIdx.x;
    int wv = t >> 6, lane = t & 63;
    int lm = lane & 31, kh = lane >> 5;
    __shared__ unsigned short As[64][40];
    f32x16 acc[2][2] = {};
    int sr = t >> 2, sc = (t & 3) * 8;
    const unsigned short* ag  = A + (size_t)(m0 + sr) * K + sc;
    const unsigned short* bg0 = BT + (size_t)(wv * 64 + lm) * K;
    const unsigned short* bg1 = BT + (size_t)(wv * 64 + 32 + lm) * K;
    for (int k0 = 0; k0 < K; k0 += 32) {
        *(short8*)&As[sr][sc] = *(const short8*)(ag + k0);
        __syncthreads();
#pragma unroll
        for (int ks = 0; ks < 32; ks += 16) {
            short8 a0 = *(const short8*)&As[lm][ks + kh * 8];
            short8 a1 = *(const short8*)&As[32 + lm][ks + kh * 8];
            short8 b0 = *(const short8*)(bg0 + k0 + ks + kh * 8);
            short8 b1 = *(const short8*)(bg1 + k0 + ks + kh * 8);
            acc[0][0] = __builtin_amdgcn_mfma_f32_32x32x16_bf16(a0, b0, acc[0][0], 0, 0, 0);
            acc[0][1] = __builtin_amdgcn_mfma_f32_32x32x16_bf16(a0, b1, acc[0][1], 0, 0, 0);
            acc[1][0] = __builtin_amdgcn_mfma_f32_32x32x16_bf16(a1, b0, acc[1][0], 0, 0, 0);
            acc[1][1] = __builtin_amdgcn_mfma_f32_32x32x16_bf16(a1, b1, acc[1][1], 0, 0, 0);
        }
        __syncthreads();
    }
    float* C = (ng == 0 ? h2 : lin) + (size_t)b * Nn * 256;
#pragma unroll
    for (int mt = 0; mt < 2; ++mt)
#pragma unroll
        for (int nt = 0; nt < 2; ++nt) {
            int colg = wv * 64 + nt * 32 + lm;
#pragma unroll
            for (int reg = 0; reg < 16; ++reg) {
                int rl = mt * 32 + 4 * kh + (reg & 3) + 8 * (reg >> 2);
                C[(size_t)(m0 + rl) * 256 + colg] = acc[mt][nt][reg];
            }
            if (ng == 0) {
                unsigned short* ctp = h2T + (size_t)b * Nn * 256 +
                                      (size_t)colg * Nn + m0 + mt * 32 + 4 * kh;
#pragma unroll
                for (int q = 0; q < 4; ++q) {
                    ushort4_t pk;
                    pk.x = f2bf(acc[mt][nt][q * 4 + 0]);
                    pk.y = f2bf(acc[mt][nt][q * 4 + 1]);
                    pk.z = f2bf(acc[mt][nt][q * 4 + 2]);
                    pk.w = f2bf(acc[mt][nt][q * 4 + 3]);
                    *(ushort4_t*)(ctp + 8 * q) = pk;
                }
            }
        }
}

// ---------------- scores + exp factors ----------------
__global__ __launch_bounds__(256) void scores_exp_kernel(
        const float* __restrict__ h, const float* __restrict__ a,
        float* __restrict__ E1p, float* __restrict__ E1n,
        float2* __restrict__ E2pn, int NperH, int H) {
    int tid = threadIdx.x;
    int lane = tid & 63, wv = tid >> 6;
    long long row = (long long)blockIdx.x * 4 + wv;
    int head = (int)((row / NperH) % H);
    const float* ap = a + (size_t)head * 2 * Oo;
    float4 x4 = ((const float4*)(h + (size_t)row * Oo))[lane];
    float4 a1 = ((const float4*)ap)[lane];
    float4 a2 = ((const float4*)(ap + Oo))[lane];
    float t1 = x4.x * a1.x + x4.y * a1.y + x4.z * a1.z + x4.w * a1.w;
    float t2 = x4.x * a2.x + x4.y * a2.y + x4.z * a2.z + x4.w * a2.w;
    for (int off = 32; off; off >>= 1) {
        t1 += __shfl_down(t1, off, 64);
        t2 += __shfl_down(t2, off, 64);
    }
    if (!lane) {
        E1p[row] = __expf(t1);
        E1n[row] = __expf(0.2f * t1);
        E2pn[row] = make_float2(__expf(t2), __expf(0.2f * t2));
    }
}

// ---------------- mh attention: 512 threads, 8 waves, j-split in block ----------------
// grid (bh=16, it=32): XCD = bh%8 pins each head pair's hT slice to one L2.
// wave w: jh = w>>2 (j-half of 1024), oq = w&3 (64 o-cols). P computed once per (i,j).
__global__ __launch_bounds__(512, 4) void attn_v4_kernel(
        const unsigned short* __restrict__ hT,
        const unsigned* __restrict__ bits,
        const float* __restrict__ E1p, const float* __restrict__ E1n,
        const float2* __restrict__ E2pn,
        unsigned short* __restrict__ outbf) {
    constexpr int ABS = 65;
    int bh = blockIdx.x, it = blockIdx.y;
    int b = bh >> 3, hd = bh & 7;
    int i0 = it * 64;
    int t = threadIdx.x, lane = t & 63;
    int w = t >> 6, jh = w >> 2, oq = w & 3;
    int lm = lane & 31, kh = lane >> 5;
    int ti = t & 63, jq = (t >> 6) & 3;   // p-compute mapping (within half jh)

    __shared__ unsigned ab[64 * ABS];                          // 16.6 KB
    __shared__ __align__(16) unsigned short ps[2][2][64][64];  // 32 KB [jh][dbuf]
    __shared__ float lred[64][9];
    __shared__ float linv[64];

    const unsigned* bb = bits + ((size_t)b * Nn + i0) * 64;
    for (int k = t; k < 64 * 64; k += 512) {
        int r = k >> 6, w0 = k & 63;
        ab[r * ABS + w0] = bb[(size_t)r * 64 + w0];
    }
    __syncthreads();   // ab visible to all before computeP

    float e1p = E1p[(size_t)bh * Nn + i0 + ti];
    float e1n = E1n[(size_t)bh * Nn + i0 + ti];
    const float4* e2base = (const float4*)(E2pn + (size_t)bh * Nn);

    const unsigned short* hTb = hT + (size_t)bh * ((size_t)Oo * Nn);
    const unsigned short* bg0 = hTb + (size_t)(oq * 64 + lm) * Nn + jh * 1024;
    const unsigned short* bg1 = hTb + (size_t)(oq * 64 + 32 + lm) * Nn + jh * 1024;

    f32x16 acc[2][2] = {};
    float lpart = 0.f;
    short8 B0[8], B1[8];

    auto loadB = [&](int c, short8* B) {
#pragma unroll
        for (int s = 0; s < 4; ++s) {
            B[2 * s]     = *(const short8*)(bg0 + c * 64 + s * 16 + kh * 8);
            B[2 * s + 1] = *(const short8*)(bg1 + c * 64 + s * 16 + kh * 8);
        }
    };
    auto computeP = [&](int c, int buf) {
        int cj = jh * 1024 + c * 64;
        unsigned word = ab[ti * ABS + ((cj >> 5) + (jq >> 1))];
        unsigned field = word >> ((jq & 1) * 16);
        const float4* ep = e2base + ((cj + jq * 16) >> 1);
        unsigned pk[8];
#pragma unroll
        for (int u = 0; u < 8; ++u) {
            float4 q = ep[u];
            float pp0 = e1p * q.x, pn0 = e1n * q.y;
            float p0 = pp0 > 1.f ? pp0 : pn0;
            p0 = ((field >> (2 * u)) & 1u) ? p0 : 0.f;
            float pp1 = e1p * q.z, pn1 = e1n * q.w;
            float p1 = pp1 > 1.f ? pp1 : pn1;
            p1 = ((field >> (2 * u + 1)) & 1u) ? p1 : 0.f;
            lpart += p0 + p1;
            __hip_bfloat162 hv = __float22bfloat162_rn(make_float2(p0, p1));
            pk[u] = *(unsigned*)&hv;
        }
        unsigned sw = ti & 7;
        uint4 v0; v0.x = pk[0]; v0.y = pk[1]; v0.z = pk[2]; v0.w = pk[3];
        uint4 v1; v1.x = pk[4]; v1.y = pk[5]; v1.z = pk[6]; v1.w = pk[7];
        *(uint4*)&ps[jh][buf][ti][((2 * jq) ^ sw) * 8]     = v0;
        *(uint4*)&ps[jh][buf][ti][((2 * jq + 1) ^ sw) * 8] = v1;
    };
    auto mfmaStep = [&](int buf, short8* B) {
        unsigned sw = lm & 7;
#pragma unroll
        for (int s = 0; s < 4; ++s) {
            short8 a0 = *(const short8*)&ps[jh][buf][lm][((2 * s + kh) ^ sw) * 8];
            short8 a1 = *(const short8*)&ps[jh][buf][32 + lm][((2 * s + kh) ^ sw) * 8];
            acc[0][0] = __builtin_amdgcn_mfma_f32_32x32x16_bf16(a0, B[2 * s],     acc[0][0], 0, 0, 0);
            acc[0][1] = __builtin_amdgcn_mfma_f32_32x32x16_bf16(a0, B[2 * s + 1], acc[0][1], 0, 0, 0);
            acc[1][0] = __builtin_amdgcn_mfma_f32_32x32x16_bf16(a1, B[2 * s],     acc[1][0], 0, 0, 0);
            acc[1][1] = __builtin_amdgcn_mfma_f32_32x32x16_bf16(a1, B[2 * s + 1], acc[1][1], 0, 0, 0);
        }
    };

    loadB(0, B0);
    computeP(0, 0);
    __syncthreads();
    for (int c = 0; c < 16; c += 2) {
        loadB(c + 1, B1);
        mfmaStep(0, B0);
        computeP(c + 1, 1);
        __syncthreads();
        if (c + 2 < 16) loadB(c + 2, B0);
        mfmaStep(1, B1);
        if (c + 2 < 16) computeP(c + 2, 0);
        __syncthreads();
    }

    // l reduction across all 8 wave-groups
    lred[ti][w] = lpart;
    __syncthreads();
    if (t < 64) {
        float s = 0.f;
#pragma unroll
        for (int k = 0; k < 8; ++k) s += lred[t][k];
        linv[t] = 1.f / s;
    }
    __syncthreads();

    // cross-half acc merge via dead ps region (two 16 KB phases), store by jh==1
    float* fbuf = (float*)ps;   // [2][64][64] f32
    for (int phase = 0; phase < 2; ++phase) {
        if (jh == 0 && (oq >> 1) == phase) {
#pragma unroll
            for (int mt = 0; mt < 2; ++mt)
#pragma unroll
                for (int nt = 0; nt < 2; ++nt)
#pragma unroll
                    for (int reg = 0; reg < 16; ++reg) {
                        int rl = mt * 32 + 4 * kh + (reg & 3) + 8 * (reg >> 2);
                        fbuf[(size_t)(oq & 1) * 4096 + rl * 64 + nt * 32 + lm] = acc[mt][nt][reg];
                    }
        }
        __syncthreads();
        if (jh == 1 && (oq >> 1) == phase) {
#pragma unroll
            for (int mt = 0; mt < 2; ++mt)
#pragma unroll
                for (int nt = 0; nt < 2; ++nt)
#pragma unroll
                    for (int reg = 0; reg < 16; ++reg) {
                        int rl = mt * 32 + 4 * kh + (reg & 3) + 8 * (reg >> 2);
                        int col = nt * 32 + lm;
                        float v = acc[mt][nt][reg] + fbuf[(size_t)(oq & 1) * 4096 + rl * 64 + col];
                        v *= linv[rl];
                        v = v > 0.f ? v : expm1f(v);   // elu
                        outbf[((size_t)b * Nn + i0 + rl) * (Hh * Oo) +
                              (size_t)hd * Oo + oq * 64 + col] = f2bf(v);
                    }
        }
        __syncthreads();
    }
}

// ---------------- pipelined MFMA attention (single-head partials) ----------------
template<int JLEN, int MODE, int SWAPXY>
__global__ __launch_bounds__(256, 2) void attn_v2_kernel(
        const unsigned short* __restrict__ hT, long long sHT,
        const unsigned* __restrict__ bits,
        const float* __restrict__ E1p, const float* __restrict__ E1n,
        const float2* __restrict__ E2pn,
        unsigned short* __restrict__ outbf, int ldo,
        float* __restrict__ pacc, float* __restrict__ plsum,
        int hshift) {
    constexpr int W = JLEN / 32, NC = JLEN / 64, ABS = W + 1;
    int it = SWAPXY ? blockIdx.y : blockIdx.x;
    int bh = SWAPXY ? blockIdx.x : blockIdx.y;
    int js = blockIdx.z;
    int b = bh >> hshift, hd = bh & ((1 << hshift) - 1);
    int i0 = it * 64, jbase = js * JLEN;
    int t = threadIdx.x, lane = t & 63;
    int wv = t >> 6, lm = lane & 31, kh = lane >> 5;
    int ti = lane, jq = wv;

    __shared__ unsigned ab[64 * ABS];
    __shared__ __align__(16) unsigned short ps[2][64][64];
    __shared__ float lred[64][5];
    __shared__ float linv[64];

    const unsigned* bb = bits + ((size_t)b * Nn + i0) * 64 + (jbase >> 5);
    for (int k = t; k < 64 * W; k += 256) {
        int r = k / W, w0 = k - r * W;
        ab[r * ABS + w0] = bb[(size_t)r * 64 + w0];
    }
    __syncthreads();

    float e1p = E1p[(size_t)bh * Nn + i0 + ti];
    float e1n = E1n[(size_t)bh * Nn + i0 + ti];
    const float4* e2base = (const float4*)(E2pn + (size_t)bh * Nn + jbase);

    const unsigned short* hTb = hT + (size_t)bh * sHT + jbase;
    const unsigned short* bg0 = hTb + (size_t)(wv * 64 + lm) * Nn;
    const unsigned short* bg1 = hTb + (size_t)(wv * 64 + 32 + lm) * Nn;

    f32x16 acc[2][2] = {};
    float lpart = 0.f;
    short8 B0[8], B1[8];

    auto loadB = [&](int c, short8* B) {
#pragma unroll
        for (int s = 0; s < 4; ++s) {
            B[2 * s]     = *(const short8*)(bg0 + c * 64 + s * 16 + kh * 8);
            B[2 * s + 1] = *(const short8*)(bg1 + c * 64 + s * 16 + kh * 8);
        }
    };
    auto computeP = [&](int c, int buf) {
        int cj = c * 64;
        unsigned word = ab[ti * ABS + ((cj >> 5) + (jq >> 1))];
        unsigned field = word >> ((jq & 1) * 16);
        const float4* ep = e2base + ((cj + jq * 16) >> 1);
        unsigned pk[8];
#pragma unroll
        for (int u = 0; u < 8; ++u) {
            float4 q = ep[u];
            float pp0 = e1p * q.x, pn0 = e1n * q.y;
            float p0 = pp0 > 1.f ? pp0 : pn0;
            p0 = ((field >> (2 * u)) & 1u) ? p0 : 0.f;
            float pp1 = e1p * q.z, pn1 = e1n * q.w;
            float p1 = pp1 > 1.f ? pp1 : pn1;
            p1 = ((field >> (2 * u + 1)) & 1u) ? p1 : 0.f;
            lpart += p0 + p1;
            __hip_bfloat162 hv = __float22bfloat162_rn(make_float2(p0, p1));
            pk[u] = *(unsigned*)&hv;
        }
        unsigned sw = ti & 7;
        uint4 v0; v0.x = pk[0]; v0.y = pk[1]; v0.z = pk[2]; v0.w = pk[3];
        uint4 v1; v1.x = pk[4]; v1.y = pk[5]; v1.z = pk[6]; v1.w = pk[7];
        *(uint4*)&ps[buf][ti][((2 * jq) ^ sw) * 8]     = v0;
        *(uint4*)&ps[buf][ti][((2 * jq + 1) ^ sw) * 8] = v1;
    };
    auto mfmaStep = [&](int buf, short8* B) {
        unsigned sw = lm & 7;
#pragma unroll
        for (int s = 0; s < 4; ++s) {
            short8 a0 = *(const short8*)&ps[buf][lm][((2 * s + kh) ^ sw) * 8];
            short8 a1 = *(const short8*)&ps[buf][32 + lm][((2 * s + kh) ^ sw) * 8];
            acc[0][0] = __builtin_amdgcn_mfma_f32_32x32x16_bf16(a0, B[2 * s],     acc[0][0], 0, 0, 0);
            acc[0][1] = __builtin_amdgcn_mfma_f32_32x32x16_bf16(a0, B[2 * s + 1], acc[0][1], 0, 0, 0);
            acc[1][0] = __builtin_amdgcn_mfma_f32_32x32x16_bf16(a1, B[2 * s],     acc[1][0], 0, 0, 0);
            acc[1][1] = __builtin_amdgcn_mfma_f32_32x32x16_bf16(a1, B[2 * s + 1], acc[1][1], 0, 0, 0);
        }
    };

    loadB(0, B0);
    computeP(0, 0);
    __syncthreads();
    for (int c = 0; c < NC; c += 2) {
        loadB(c + 1, B1);
        mfmaStep(0, B0);
        computeP(c + 1, 1);
        __syncthreads();
        if (c + 2 < NC) loadB(c + 2, B0);
        mfmaStep(1, B1);
        if (c + 2 < NC) computeP(c + 2, 0);
        __syncthreads();
    }

    lred[ti][jq] = lpart;
    __syncthreads();
    if (MODE == 0) {
        if (t < 64) linv[t] = 1.f / (lred[t][0] + lred[t][1] + lred[t][2] + lred[t][3]);
        __syncthreads();
#pragma unroll
        for (int mt = 0; mt < 2; ++mt)
#pragma unroll
            for (int nt = 0; nt < 2; ++nt) {
                int o = wv * 64 + nt * 32 + lm;
#pragma unroll
                for (int reg = 0; reg < 16; ++reg) {
                    int rl = mt * 32 + 4 * kh + (reg & 3) + 8 * (reg >> 2);
                    float v = acc[mt][nt][reg] * linv[rl];
                    v = v > 0.f ? v : expm1f(v);
                    outbf[((size_t)b * Nn + i0 + rl) * ldo + (size_t)hd * Oo + o] = f2bf(v);
                }
            }
    } else {
        if (t < 64)
            plsum[((size_t)js * Bb + b) * Nn + i0 + t] =
                lred[t][0] + lred[t][1] + lred[t][2] + lred[t][3];
        float* pa = pacc + (((size_t)js * Bb + b) * Nn) * 256;
#pragma unroll
        for (int mt = 0; mt < 2; ++mt)
#pragma unroll
            for (int nt = 0; nt < 2; ++nt) {
                int o = wv * 64 + nt * 32 + lm;
#pragma unroll
                for (int reg = 0; reg < 16; ++reg) {
                    int rl = mt * 32 + 4 * kh + (reg & 3) + 8 * (reg >> 2);
                    pa[(size_t)(i0 + rl) * 256 + o] = acc[mt][nt][reg];
                }
            }
    }
}

// ---------------- combine partials: x2 = Σacc/Σl + lin + b ----------------
__global__ __launch_bounds__(256) void combine_kernel(
        const float* __restrict__ pacc, const float* __restrict__ plsum,
        const float* __restrict__ lin, const float* __restrict__ bias,
        unsigned short* __restrict__ out) {
    int gid = blockIdx.x * 256 + threadIdx.x;
    int row = gid >> 6;
    int o4 = gid & 63;
    size_t ps4 = (size_t)Bb * Nn * 64;
    const float4* p = (const float4*)pacc + (size_t)row * 64 + o4;
    float4 s = p[0], sa = p[ps4], sb = p[2 * ps4], sc = p[3 * ps4];
    s.x += sa.x + sb.x + sc.x; s.y += sa.y + sb.y + sc.y;
    s.z += sa.z + sb.z + sc.z; s.w += sa.w + sb.w + sc.w;
    int BN = Bb * Nn;
    float li = 1.f / (plsum[row] + plsum[row + BN] + plsum[row + 2 * BN] + plsum[row + 3 * BN]);
    float4 lv = ((const float4*)lin)[(size_t)row * 64 + o4];
    float4 bv = ((const float4*)bias)[o4];
    float4 v;
    v.x = s.x * li + lv.x + bv.x; v.y = s.y * li + lv.y + bv.y;
    v.z = s.z * li + lv.z + bv.z; v.w = s.w * li + lv.w + bv.w;
    __hip_bfloat162 h0 = __float22bfloat162_rn(make_float2(v.x, v.y));
    __hip_bfloat162 h1 = __float22bfloat162_rn(make_float2(v.z, v.w));
    uint2 st; st.x = *(unsigned*)&h0; st.y = *(unsigned*)&h1;
    *(uint2*)(out + (size_t)gid * 4) = st;
}

extern "C" void kernel_launch(void* const* d_in, const int* in_sizes, int n_in,
                              void* d_out, int out_size, void* d_ws, size_t ws_size,
                              hipStream_t stream) {
    const float* x       = (const float*)d_in[0];
    const float* adj     = (const float*)d_in[1];
    const float* W_heads = (const float*)d_in[3];
    const float* a_heads = (const float*)d_in[4];
    const float* W_out   = (const float*)d_in[5];
    const float* a_out   = (const float*)d_in[6];
    const float* W_lin   = (const float*)d_in[7];
    const float* b_lin   = (const float*)d_in[8];
    const float* W_ln    = (const float*)d_in[9];
    const float* b_ln    = (const float*)d_in[10];

    char* w = (char*)d_ws;
    float* h        = (float*)(w);                    // [16][2048][256] f32
    float* lin      = (float*)(w + 33554432);
    float* h2       = (float*)(w + 37748736);
    float* E1p_mh   = (float*)(w + 41943040);
    float* E1n_mh   = (float*)(w + 42074112);
    float2* E2pn_mh = (float2*)(w + 42205184);
    float* E1p_sh   = (float*)(w + 42467328);
    float* E1n_sh   = (float*)(w + 42483712);
    float2* E2pn_sh = (float2*)(w + 42500096);
    unsigned long long* bits = (unsigned long long*)(w + 42532864);
    unsigned short* x_bf  = (unsigned short*)(w + 43581440);
    unsigned short* x2_bf = (unsigned short*)(w + 43581440);
    unsigned short* WhT   = (unsigned short*)(w + 49872896);
    unsigned short* WoT   = (unsigned short*)(w + 53018624);
    unsigned short* Wl_bf = (unsigned short*)(w + 54067200);
    unsigned short* Wn_bf = (unsigned short*)(w + 55115776);
    unsigned short* hT    = (unsigned short*)(w + 55246848);
    unsigned short* h2T   = (unsigned short*)(w + 72024064);
    unsigned short* x1_bf = (unsigned short*)(w + 74121216);
    float* pacc  = h;
    float* plsum = h + 4194304;

    // 0) prep
    adjbits_kernel<<<(Bb * Nn * Nn) / 256, 256, 0, stream>>>(adj, bits);
    cast_bf_kernel<<<(Bb * Nn * Ff) / 1024, 256, 0, stream>>>(x, x_bf);
    cast_bf_kernel<<<(Oo * Hh * Oo) / 1024, 256, 0, stream>>>(W_lin, Wl_bf);
    cast_bf_kernel<<<(Oo * Oo) / 1024, 256, 0, stream>>>(W_ln, Wn_bf);
    transpose_bf_kernel<<<dim3(Oo / 32, Ff / 32, Hh), 256, 0, stream>>>(W_heads, WhT, Ff, Oo);
    transpose_bf_kernel<<<dim3(Oo / 32, (Hh * Oo) / 32, 1), 256, 0, stream>>>(W_out, WoT, Hh * Oo, Oo);

    // 1) h = x @ W_heads (+ hT bf16)
    gemm_bf_kernel<<<dim3(Nn / 64, 1, Bb * Hh), 256, 0, stream>>>(
        x_bf, Ff, (long long)Nn * Ff, 3, WhT, (long long)Ff * Oo, 7,
        h, (long long)Nn * Oo, hT, (long long)Nn * Oo, Nn, nullptr, 1);
    // 2) scores + exp factors (mh)
    scores_exp_kernel<<<(Bb * Hh * Nn) / 4, 256, 0, stream>>>(h, a_heads, E1p_mh, E1n_mh, E2pn_mh, Nn, Hh);
    // 3) multihead attention + elu -> x1_bf  (512-thread blocks, j-split in block)
    attn_v4_kernel<<<dim3(Bb * Hh, Nn / 64), 512, 0, stream>>>(
        hT, (const unsigned*)bits, E1p_mh, E1n_mh, E2pn_mh, x1_bf);
    // 4+5) fused: h2 = x1 @ W_out (+ h2T bf16) and lin = x1 @ W_lin^T
    gemm_dual_kernel<<<dim3(Nn / 64, 2, Bb), 256, 0, stream>>>(
        x1_bf, Hh * Oo, (long long)Nn * Hh * Oo, WoT, h2, h2T, lin);
    // 6) scores + exp factors (sh)
    scores_exp_kernel<<<(Bb * Nn) / 4, 256, 0, stream>>>(h2, a_out, E1p_sh, E1n_sh, E2pn_sh, Nn, 1);
    // 7) single-head attention, 4-way j-split partials
    attn_v2_kernel<512, 1, 0><<<dim3(Nn / 64, Bb, 4), 256, 0, stream>>>(
        h2T, (long long)Oo * Nn, (const unsigned*)bits, E1p_sh, E1n_sh, E2pn_sh,
        nullptr, 0, pacc, plsum, 0);
    // 8) combine -> x2_bf
    combine_kernel<<<(Bb * Nn * 64) / 256, 256, 0, stream>>>(pacc, plsum, lin, b_lin, x2_bf);
    // 9) out = relu(x2 @ W_ln^T + b_ln)
    gemm_bf_kernel<<<dim3(Nn / 64, 1, Bb), 256, 0, stream>>>(
        x2_bf, Oo, (long long)Nn * Oo, 0, Wn_bf, 0, 0,
        (float*)d_out, (long long)Nn * Oo, nullptr, 0, Nn, b_ln, 2);
}

// Round 9
// 376.059 us; speedup vs baseline: 1.3761x; 1.3761x over previous
//
#include <hip/hip_runtime.h>
#include <hip/hip_bf16.h>

constexpr int Bb = 2, Nn = 2048, Ff = 768, Hh = 8, Oo = 256;

typedef __attribute__((ext_vector_type(8)))  short   short8;
typedef __attribute__((ext_vector_type(16))) float   f32x16;
typedef __attribute__((ext_vector_type(4)))  unsigned short ushort4_t;

__device__ inline unsigned short f2bf(float f) {
    unsigned u = __float_as_uint(f);
    u = (u + 0x7FFFu + ((u >> 16) & 1u)) >> 16;   // RNE
    return (unsigned short)u;
}

// ---------------- adjacency bitmask ----------------
__global__ __launch_bounds__(256) void adjbits_kernel(
        const float* __restrict__ adj, unsigned long long* __restrict__ bits) {
    size_t gid = (size_t)blockIdx.x * 256 + threadIdx.x;
    float v = adj[gid];
    unsigned long long m = __ballot(v > 0.f);
    if ((threadIdx.x & 63) == 0) bits[gid >> 6] = m;
}

// ---------------- f32 -> bf16 flat cast ----------------
__global__ __launch_bounds__(256) void cast_bf_kernel(
        const float* __restrict__ in, unsigned short* __restrict__ out) {
    size_t i = (size_t)blockIdx.x * 256 + threadIdx.x;
    float4 v = ((const float4*)in)[i];
    ushort4_t o;
    o.x = f2bf(v.x); o.y = f2bf(v.y); o.z = f2bf(v.z); o.w = f2bf(v.w);
    ((ushort4_t*)out)[i] = o;
}

// ---------------- [z][R][C] f32 -> [z][C][R] bf16 transpose ----------------
__global__ __launch_bounds__(256) void transpose_bf_kernel(
        const float* __restrict__ in, unsigned short* __restrict__ out, int R, int C) {
    __shared__ float tile[32][33];
    int c0 = blockIdx.x * 32, r0 = blockIdx.y * 32;
    const float* ib = in + (size_t)blockIdx.z * R * C;
    unsigned short* ob = out + (size_t)blockIdx.z * R * C;
    int tx = threadIdx.x & 31, ty = threadIdx.x >> 5;
    for (int k = 0; k < 32; k += 8)
        tile[ty + k][tx] = ib[(size_t)(r0 + ty + k) * C + c0 + tx];
    __syncthreads();
    for (int k = 0; k < 32; k += 8)
        ob[(size_t)(c0 + ty + k) * R + r0 + tx] = f2bf(tile[tx][ty + k]);
}

// ---------------- MFMA GEMM: C[M x 256] = A[M x K] * BT[256 x K]^T ----------------
__global__ __launch_bounds__(256) void gemm_bf_kernel(
        const unsigned short* __restrict__ A, int K, long long sA, int bAshift,
        const unsigned short* __restrict__ BT, long long sB, int bmask,
        float* __restrict__ C, long long sC,
        unsigned short* __restrict__ CT, long long sCT, int Mtot,
        const float* __restrict__ bias, int mode) {
    int z = blockIdx.z;
    A  += (size_t)(z >> bAshift) * sA;
    BT += (size_t)(z & bmask) * sB;
    C  += (size_t)z * sC;
    if (CT) CT += (size_t)z * sCT;
    int m0 = blockIdx.x * 64;
    int t = threadIdx.x;
    int wv = t >> 6, lane = t & 63;
    int lm = lane & 31, kh = lane >> 5;
    __shared__ unsigned short As[64][40];
    f32x16 acc[2][2] = {};
    int sr = t >> 2, sc = (t & 3) * 8;
    const unsigned short* ag  = A + (size_t)(m0 + sr) * K + sc;
    const unsigned short* bg0 = BT + (size_t)(wv * 64 + lm) * K;
    const unsigned short* bg1 = BT + (size_t)(wv * 64 + 32 + lm) * K;
    for (int k0 = 0; k0 < K; k0 += 32) {
        *(short8*)&As[sr][sc] = *(const short8*)(ag + k0);
        __syncthreads();
#pragma unroll
        for (int ks = 0; ks < 32; ks += 16) {
            short8 a0 = *(const short8*)&As[lm][ks + kh * 8];
            short8 a1 = *(const short8*)&As[32 + lm][ks + kh * 8];
            short8 b0 = *(const short8*)(bg0 + k0 + ks + kh * 8);
            short8 b1 = *(const short8*)(bg1 + k0 + ks + kh * 8);
            acc[0][0] = __builtin_amdgcn_mfma_f32_32x32x16_bf16(a0, b0, acc[0][0], 0, 0, 0);
            acc[0][1] = __builtin_amdgcn_mfma_f32_32x32x16_bf16(a0, b1, acc[0][1], 0, 0, 0);
            acc[1][0] = __builtin_amdgcn_mfma_f32_32x32x16_bf16(a1, b0, acc[1][0], 0, 0, 0);
            acc[1][1] = __builtin_amdgcn_mfma_f32_32x32x16_bf16(a1, b1, acc[1][1], 0, 0, 0);
        }
        __syncthreads();
    }
#pragma unroll
    for (int mt = 0; mt < 2; ++mt)
#pragma unroll
        for (int nt = 0; nt < 2; ++nt) {
            int colg = wv * 64 + nt * 32 + lm;
            float bv = (mode == 2) ? bias[colg] : 0.f;
#pragma unroll
            for (int reg = 0; reg < 16; ++reg) {
                int rl = mt * 32 + 4 * kh + (reg & 3) + 8 * (reg >> 2);
                float v = acc[mt][nt][reg];
                if (mode == 2) { v += bv; v = fmaxf(v, 0.f); }
                C[(size_t)(m0 + rl) * 256 + colg] = v;
            }
            if (mode == 1) {
                unsigned short* ctp = CT + (size_t)colg * Mtot + m0 + mt * 32 + 4 * kh;
#pragma unroll
                for (int q = 0; q < 4; ++q) {
                    ushort4_t pk;
                    pk.x = f2bf(acc[mt][nt][q * 4 + 0]);
                    pk.y = f2bf(acc[mt][nt][q * 4 + 1]);
                    pk.z = f2bf(acc[mt][nt][q * 4 + 2]);
                    pk.w = f2bf(acc[mt][nt][q * 4 + 3]);
                    *(ushort4_t*)(ctp + 8 * q) = pk;
                }
            }
        }
}

// ---------------- dual MFMA GEMM: x1 @ [WoT ; Wl]^T in one launch ----------------
__global__ __launch_bounds__(256) void gemm_dual_kernel(
        const unsigned short* __restrict__ A, int K, long long sA,
        const unsigned short* __restrict__ BT,
        float* __restrict__ h2, unsigned short* __restrict__ h2T,
        float* __restrict__ lin) {
    int b = blockIdx.z, ng = blockIdx.y;
    A += (size_t)b * sA;
    BT += (size_t)ng * 256 * K;
    int m0 = blockIdx.x * 64;
    int t = threadIdx.x;
    int wv = t >> 6, lane = t & 63;
    int lm = lane & 31, kh = lane >> 5;
    __shared__ unsigned short As[64][40];
    f32x16 acc[2][2] = {};
    int sr = t >> 2, sc = (t & 3) * 8;
    const unsigned short* ag  = A + (size_t)(m0 + sr) * K + sc;
    const unsigned short* bg0 = BT + (size_t)(wv * 64 + lm) * K;
    const unsigned short* bg1 = BT + (size_t)(wv * 64 + 32 + lm) * K;
    for (int k0 = 0; k0 < K; k0 += 32) {
        *(short8*)&As[sr][sc] = *(const short8*)(ag + k0);
        __syncthreads();
#pragma unroll
        for (int ks = 0; ks < 32; ks += 16) {
            short8 a0 = *(const short8*)&As[lm][ks + kh * 8];
            short8 a1 = *(const short8*)&As[32 + lm][ks + kh * 8];
            short8 b0 = *(const short8*)(bg0 + k0 + ks + kh * 8);
            short8 b1 = *(const short8*)(bg1 + k0 + ks + kh * 8);
            acc[0][0] = __builtin_amdgcn_mfma_f32_32x32x16_bf16(a0, b0, acc[0][0], 0, 0, 0);
            acc[0][1] = __builtin_amdgcn_mfma_f32_32x32x16_bf16(a0, b1, acc[0][1], 0, 0, 0);
            acc[1][0] = __builtin_amdgcn_mfma_f32_32x32x16_bf16(a1, b0, acc[1][0], 0, 0, 0);
            acc[1][1] = __builtin_amdgcn_mfma_f32_32x32x16_bf16(a1, b1, acc[1][1], 0, 0, 0);
        }
        __syncthreads();
    }
    float* C = (ng == 0 ? h2 : lin) + (size_t)b * Nn * 256;
#pragma unroll
    for (int mt = 0; mt < 2; ++mt)
#pragma unroll
        for (int nt = 0; nt < 2; ++nt) {
            int colg = wv * 64 + nt * 32 + lm;
#pragma unroll
            for (int reg = 0; reg < 16; ++reg) {
                int rl = mt * 32 + 4 * kh + (reg & 3) + 8 * (reg >> 2);
                C[(size_t)(m0 + rl) * 256 + colg] = acc[mt][nt][reg];
            }
            if (ng == 0) {
                unsigned short* ctp = h2T + (size_t)b * Nn * 256 +
                                      (size_t)colg * Nn + m0 + mt * 32 + 4 * kh;
#pragma unroll
                for (int q = 0; q < 4; ++q) {
                    ushort4_t pk;
                    pk.x = f2bf(acc[mt][nt][q * 4 + 0]);
                    pk.y = f2bf(acc[mt][nt][q * 4 + 1]);
                    pk.z = f2bf(acc[mt][nt][q * 4 + 2]);
                    pk.w = f2bf(acc[mt][nt][q * 4 + 3]);
                    *(ushort4_t*)(ctp + 8 * q) = pk;
                }
            }
        }
}

// ---------------- scores + exp factors ----------------
__global__ __launch_bounds__(256) void scores_exp_kernel(
        const float* __restrict__ h, const float* __restrict__ a,
        float* __restrict__ E1p, float* __restrict__ E1n,
        float2* __restrict__ E2pn, int NperH, int H) {
    int tid = threadIdx.x;
    int lane = tid & 63, wv = tid >> 6;
    long long row = (long long)blockIdx.x * 4 + wv;
    int head = (int)((row / NperH) % H);
    const float* ap = a + (size_t)head * 2 * Oo;
    float4 x4 = ((const float4*)(h + (size_t)row * Oo))[lane];
    float4 a1 = ((const float4*)ap)[lane];
    float4 a2 = ((const float4*)(ap + Oo))[lane];
    float t1 = x4.x * a1.x + x4.y * a1.y + x4.z * a1.z + x4.w * a1.w;
    float t2 = x4.x * a2.x + x4.y * a2.y + x4.z * a2.z + x4.w * a2.w;
    for (int off = 32; off; off >>= 1) {
        t1 += __shfl_down(t1, off, 64);
        t2 += __shfl_down(t2, off, 64);
    }
    if (!lane) {
        E1p[row] = __expf(t1);
        E1n[row] = __expf(0.2f * t1);
        E2pn[row] = make_float2(__expf(t2), __expf(0.2f * t2));
    }
}

// ---------------- mh attention: 512 threads, 8 waves, j-split in block ----------------
// grid (bh=16, it=32): XCD = bh%8 pins each head's hT slice to one L2.
// wave w: jh = w>>2 (j-half of 1024), oq = w&3 (64 o-cols).
// B-prefetch is 1-step lookahead ping-pong (32 regs) to fit the 128-reg budget
// at 4 waves/EU (R8's 8-step dbuf spilled: 585 MB scratch traffic).
__global__ __launch_bounds__(512, 4) void attn_v4_kernel(
        const unsigned short* __restrict__ hT,
        const unsigned* __restrict__ bits,
        const float* __restrict__ E1p, const float* __restrict__ E1n,
        const float2* __restrict__ E2pn,
        unsigned short* __restrict__ outbf) {
    constexpr int ABS = 65;
    int bh = blockIdx.x, it = blockIdx.y;
    int b = bh >> 3, hd = bh & 7;
    int i0 = it * 64;
    int t = threadIdx.x, lane = t & 63;
    int w = t >> 6, jh = w >> 2, oq = w & 3;
    int lm = lane & 31, kh = lane >> 5;
    int ti = t & 63, jq = (t >> 6) & 3;   // p-compute mapping (within half jh)

    __shared__ unsigned ab[64 * ABS];                          // 16.6 KB
    __shared__ __align__(16) unsigned short ps[2][2][64][64];  // 32 KB [jh][dbuf]
    __shared__ float lred[64][9];
    __shared__ float linv[64];

    const unsigned* bb = bits + ((size_t)b * Nn + i0) * 64;
    for (int k = t; k < 64 * 64; k += 512) {
        int r = k >> 6, w0 = k & 63;
        ab[r * ABS + w0] = bb[(size_t)r * 64 + w0];
    }

    float e1p = E1p[(size_t)bh * Nn + i0 + ti];
    float e1n = E1n[(size_t)bh * Nn + i0 + ti];
    const float4* e2base = (const float4*)(E2pn + (size_t)bh * Nn);

    const unsigned short* hTb = hT + (size_t)bh * ((size_t)Oo * Nn);
    const unsigned short* bg0 = hTb + (size_t)(oq * 64 + lm) * Nn + jh * 1024;
    const unsigned short* bg1 = hTb + (size_t)(oq * 64 + 32 + lm) * Nn + jh * 1024;

    f32x16 acc[2][2] = {};
    float lpart = 0.f;
    short8 Bbuf[2][2];   // ping-pong, 1-step lookahead

    auto loadBs = [&](int c, int s, int slot) {
        Bbuf[slot][0] = *(const short8*)(bg0 + c * 64 + s * 16 + kh * 8);
        Bbuf[slot][1] = *(const short8*)(bg1 + c * 64 + s * 16 + kh * 8);
    };
    auto computeP = [&](int c, int buf) {
        int cj = jh * 1024 + c * 64;
        unsigned word = ab[ti * ABS + ((cj >> 5) + (jq >> 1))];
        unsigned field = word >> ((jq & 1) * 16);
        const float4* ep = e2base + ((cj + jq * 16) >> 1);
        unsigned pk[8];
#pragma unroll
        for (int u = 0; u < 8; ++u) {
            float4 q = ep[u];
            float pp0 = e1p * q.x, pn0 = e1n * q.y;
            float p0 = pp0 > 1.f ? pp0 : pn0;
            p0 = ((field >> (2 * u)) & 1u) ? p0 : 0.f;
            float pp1 = e1p * q.z, pn1 = e1n * q.w;
            float p1 = pp1 > 1.f ? pp1 : pn1;
            p1 = ((field >> (2 * u + 1)) & 1u) ? p1 : 0.f;
            lpart += p0 + p1;
            __hip_bfloat162 hv = __float22bfloat162_rn(make_float2(p0, p1));
            pk[u] = *(unsigned*)&hv;
        }
        unsigned sw = ti & 7;
        uint4 v0; v0.x = pk[0]; v0.y = pk[1]; v0.z = pk[2]; v0.w = pk[3];
        uint4 v1; v1.x = pk[4]; v1.y = pk[5]; v1.z = pk[6]; v1.w = pk[7];
        *(uint4*)&ps[jh][buf][ti][((2 * jq) ^ sw) * 8]     = v0;
        *(uint4*)&ps[jh][buf][ti][((2 * jq + 1) ^ sw) * 8] = v1;
    };
    auto mfmaS = [&](int buf, int s, int slot) {
        unsigned sw = lm & 7;
        short8 a0 = *(const short8*)&ps[jh][buf][lm][((2 * s + kh) ^ sw) * 8];
        short8 a1 = *(const short8*)&ps[jh][buf][32 + lm][((2 * s + kh) ^ sw) * 8];
        acc[0][0] = __builtin_amdgcn_mfma_f32_32x32x16_bf16(a0, Bbuf[slot][0], acc[0][0], 0, 0, 0);
        acc[0][1] = __builtin_amdgcn_mfma_f32_32x32x16_bf16(a0, Bbuf[slot][1], acc[0][1], 0, 0, 0);
        acc[1][0] = __builtin_amdgcn_mfma_f32_32x32x16_bf16(a1, Bbuf[slot][0], acc[1][0], 0, 0, 0);
        acc[1][1] = __builtin_amdgcn_mfma_f32_32x32x16_bf16(a1, Bbuf[slot][1], acc[1][1], 0, 0, 0);
    };

    __syncthreads();   // ab staged
    computeP(0, 0);
    loadBs(0, 0, 0);
    __syncthreads();   // ps[.][0] ready
    for (int c = 0; c < 16; ++c) {
        int cb = c & 1, nb = cb ^ 1;
        if (c + 1 < 16) computeP(c + 1, nb);
        // s-pipeline: prefetch (c,s+1) (or (c+1,0)) while mfma (c,s)
        loadBs(c, 1, 1);            mfmaS(cb, 0, 0);
        loadBs(c, 2, 0);            mfmaS(cb, 1, 1);
        loadBs(c, 3, 1);            mfmaS(cb, 2, 0);
        if (c + 1 < 16) loadBs(c + 1, 0, 0);
        mfmaS(cb, 3, 1);
        __syncthreads();
    }

    // l reduction across all 8 wave-groups
    lred[ti][w] = lpart;
    __syncthreads();
    if (t < 64) {
        float s = 0.f;
#pragma unroll
        for (int k = 0; k < 8; ++k) s += lred[t][k];
        linv[t] = 1.f / s;
    }
    __syncthreads();

    // cross-half acc merge via dead ps region (two 16 KB phases), store by jh==1
    float* fbuf = (float*)ps;   // [2][64][64] f32
    for (int phase = 0; phase < 2; ++phase) {
        if (jh == 0 && (oq >> 1) == phase) {
#pragma unroll
            for (int mt = 0; mt < 2; ++mt)
#pragma unroll
                for (int nt = 0; nt < 2; ++nt)
#pragma unroll
                    for (int reg = 0; reg < 16; ++reg) {
                        int rl = mt * 32 + 4 * kh + (reg & 3) + 8 * (reg >> 2);
                        fbuf[(size_t)(oq & 1) * 4096 + rl * 64 + nt * 32 + lm] = acc[mt][nt][reg];
                    }
        }
        __syncthreads();
        if (jh == 1 && (oq >> 1) == phase) {
#pragma unroll
            for (int mt = 0; mt < 2; ++mt)
#pragma unroll
                for (int nt = 0; nt < 2; ++nt)
#pragma unroll
                    for (int reg = 0; reg < 16; ++reg) {
                        int rl = mt * 32 + 4 * kh + (reg & 3) + 8 * (reg >> 2);
                        int col = nt * 32 + lm;
                        float v = acc[mt][nt][reg] + fbuf[(size_t)(oq & 1) * 4096 + rl * 64 + col];
                        v *= linv[rl];
                        v = v > 0.f ? v : expm1f(v);   // elu
                        outbf[((size_t)b * Nn + i0 + rl) * (Hh * Oo) +
                              (size_t)hd * Oo + oq * 64 + col] = f2bf(v);
                    }
        }
        __syncthreads();
    }
}

// ---------------- pipelined MFMA attention (single-head partials) ----------------
template<int JLEN, int MODE, int SWAPXY>
__global__ __launch_bounds__(256, 2) void attn_v2_kernel(
        const unsigned short* __restrict__ hT, long long sHT,
        const unsigned* __restrict__ bits,
        const float* __restrict__ E1p, const float* __restrict__ E1n,
        const float2* __restrict__ E2pn,
        unsigned short* __restrict__ outbf, int ldo,
        float* __restrict__ pacc, float* __restrict__ plsum,
        int hshift) {
    constexpr int W = JLEN / 32, NC = JLEN / 64, ABS = W + 1;
    int it = SWAPXY ? blockIdx.y : blockIdx.x;
    int bh = SWAPXY ? blockIdx.x : blockIdx.y;
    int js = blockIdx.z;
    int b = bh >> hshift, hd = bh & ((1 << hshift) - 1);
    int i0 = it * 64, jbase = js * JLEN;
    int t = threadIdx.x, lane = t & 63;
    int wv = t >> 6, lm = lane & 31, kh = lane >> 5;
    int ti = lane, jq = wv;

    __shared__ unsigned ab[64 * ABS];
    __shared__ __align__(16) unsigned short ps[2][64][64];
    __shared__ float lred[64][5];
    __shared__ float linv[64];

    const unsigned* bb = bits + ((size_t)b * Nn + i0) * 64 + (jbase >> 5);
    for (int k = t; k < 64 * W; k += 256) {
        int r = k / W, w0 = k - r * W;
        ab[r * ABS + w0] = bb[(size_t)r * 64 + w0];
    }
    __syncthreads();

    float e1p = E1p[(size_t)bh * Nn + i0 + ti];
    float e1n = E1n[(size_t)bh * Nn + i0 + ti];
    const float4* e2base = (const float4*)(E2pn + (size_t)bh * Nn + jbase);

    const unsigned short* hTb = hT + (size_t)bh * sHT + jbase;
    const unsigned short* bg0 = hTb + (size_t)(wv * 64 + lm) * Nn;
    const unsigned short* bg1 = hTb + (size_t)(wv * 64 + 32 + lm) * Nn;

    f32x16 acc[2][2] = {};
    float lpart = 0.f;
    short8 B0[8], B1[8];

    auto loadB = [&](int c, short8* B) {
#pragma unroll
        for (int s = 0; s < 4; ++s) {
            B[2 * s]     = *(const short8*)(bg0 + c * 64 + s * 16 + kh * 8);
            B[2 * s + 1] = *(const short8*)(bg1 + c * 64 + s * 16 + kh * 8);
        }
    };
    auto computeP = [&](int c, int buf) {
        int cj = c * 64;
        unsigned word = ab[ti * ABS + ((cj >> 5) + (jq >> 1))];
        unsigned field = word >> ((jq & 1) * 16);
        const float4* ep = e2base + ((cj + jq * 16) >> 1);
        unsigned pk[8];
#pragma unroll
        for (int u = 0; u < 8; ++u) {
            float4 q = ep[u];
            float pp0 = e1p * q.x, pn0 = e1n * q.y;
            float p0 = pp0 > 1.f ? pp0 : pn0;
            p0 = ((field >> (2 * u)) & 1u) ? p0 : 0.f;
            float pp1 = e1p * q.z, pn1 = e1n * q.w;
            float p1 = pp1 > 1.f ? pp1 : pn1;
            p1 = ((field >> (2 * u + 1)) & 1u) ? p1 : 0.f;
            lpart += p0 + p1;
            __hip_bfloat162 hv = __float22bfloat162_rn(make_float2(p0, p1));
            pk[u] = *(unsigned*)&hv;
        }
        unsigned sw = ti & 7;
        uint4 v0; v0.x = pk[0]; v0.y = pk[1]; v0.z = pk[2]; v0.w = pk[3];
        uint4 v1; v1.x = pk[4]; v1.y = pk[5]; v1.z = pk[6]; v1.w = pk[7];
        *(uint4*)&ps[buf][ti][((2 * jq) ^ sw) * 8]     = v0;
        *(uint4*)&ps[buf][ti][((2 * jq + 1) ^ sw) * 8] = v1;
    };
    auto mfmaStep = [&](int buf, short8* B) {
        unsigned sw = lm & 7;
#pragma unroll
        for (int s = 0; s < 4; ++s) {
            short8 a0 = *(const short8*)&ps[buf][lm][((2 * s + kh) ^ sw) * 8];
            short8 a1 = *(const short8*)&ps[buf][32 + lm][((2 * s + kh) ^ sw) * 8];
            acc[0][0] = __builtin_amdgcn_mfma_f32_32x32x16_bf16(a0, B[2 * s],     acc[0][0], 0, 0, 0);
            acc[0][1] = __builtin_amdgcn_mfma_f32_32x32x16_bf16(a0, B[2 * s + 1], acc[0][1], 0, 0, 0);
            acc[1][0] = __builtin_amdgcn_mfma_f32_32x32x16_bf16(a1, B[2 * s],     acc[1][0], 0, 0, 0);
            acc[1][1] = __builtin_amdgcn_mfma_f32_32x32x16_bf16(a1, B[2 * s + 1], acc[1][1], 0, 0, 0);
        }
    };

    loadB(0, B0);
    computeP(0, 0);
    __syncthreads();
    for (int c = 0; c < NC; c += 2) {
        loadB(c + 1, B1);
        mfmaStep(0, B0);
        computeP(c + 1, 1);
        __syncthreads();
        if (c + 2 < NC) loadB(c + 2, B0);
        mfmaStep(1, B1);
        if (c + 2 < NC) computeP(c + 2, 0);
        __syncthreads();
    }

    lred[ti][jq] = lpart;
    __syncthreads();
    if (MODE == 0) {
        if (t < 64) linv[t] = 1.f / (lred[t][0] + lred[t][1] + lred[t][2] + lred[t][3]);
        __syncthreads();
#pragma unroll
        for (int mt = 0; mt < 2; ++mt)
#pragma unroll
            for (int nt = 0; nt < 2; ++nt) {
                int o = wv * 64 + nt * 32 + lm;
#pragma unroll
                for (int reg = 0; reg < 16; ++reg) {
                    int rl = mt * 32 + 4 * kh + (reg & 3) + 8 * (reg >> 2);
                    float v = acc[mt][nt][reg] * linv[rl];
                    v = v > 0.f ? v : expm1f(v);
                    outbf[((size_t)b * Nn + i0 + rl) * ldo + (size_t)hd * Oo + o] = f2bf(v);
                }
            }
    } else {
        if (t < 64)
            plsum[((size_t)js * Bb + b) * Nn + i0 + t] =
                lred[t][0] + lred[t][1] + lred[t][2] + lred[t][3];
        float* pa = pacc + (((size_t)js * Bb + b) * Nn) * 256;
#pragma unroll
        for (int mt = 0; mt < 2; ++mt)
#pragma unroll
            for (int nt = 0; nt < 2; ++nt) {
                int o = wv * 64 + nt * 32 + lm;
#pragma unroll
                for (int reg = 0; reg < 16; ++reg) {
                    int rl = mt * 32 + 4 * kh + (reg & 3) + 8 * (reg >> 2);
                    pa[(size_t)(i0 + rl) * 256 + o] = acc[mt][nt][reg];
                }
            }
    }
}

// ---------------- combine 8 partials: x2 = Σacc/Σl + lin + b ----------------
__global__ __launch_bounds__(256) void combine8_kernel(
        const float* __restrict__ pacc, const float* __restrict__ plsum,
        const float* __restrict__ lin, const float* __restrict__ bias,
        unsigned short* __restrict__ out) {
    int gid = blockIdx.x * 256 + threadIdx.x;
    int row = gid >> 6;
    int o4 = gid & 63;
    size_t ps4 = (size_t)Bb * Nn * 64;
    const float4* p = (const float4*)pacc + (size_t)row * 64 + o4;
    float4 s = p[0];
#pragma unroll
    for (int k = 1; k < 8; ++k) {
        float4 q = p[k * ps4];
        s.x += q.x; s.y += q.y; s.z += q.z; s.w += q.w;
    }
    int BN = Bb * Nn;
    float lsum = 0.f;
#pragma unroll
    for (int k = 0; k < 8; ++k) lsum += plsum[row + k * BN];
    float li = 1.f / lsum;
    float4 lv = ((const float4*)lin)[(size_t)row * 64 + o4];
    float4 bv = ((const float4*)bias)[o4];
    float4 v;
    v.x = s.x * li + lv.x + bv.x; v.y = s.y * li + lv.y + bv.y;
    v.z = s.z * li + lv.z + bv.z; v.w = s.w * li + lv.w + bv.w;
    __hip_bfloat162 h0 = __float22bfloat162_rn(make_float2(v.x, v.y));
    __hip_bfloat162 h1 = __float22bfloat162_rn(make_float2(v.z, v.w));
    uint2 st; st.x = *(unsigned*)&h0; st.y = *(unsigned*)&h1;
    *(uint2*)(out + (size_t)gid * 4) = st;
}

extern "C" void kernel_launch(void* const* d_in, const int* in_sizes, int n_in,
                              void* d_out, int out_size, void* d_ws, size_t ws_size,
                              hipStream_t stream) {
    const float* x       = (const float*)d_in[0];
    const float* adj     = (const float*)d_in[1];
    const float* W_heads = (const float*)d_in[3];
    const float* a_heads = (const float*)d_in[4];
    const float* W_out   = (const float*)d_in[5];
    const float* a_out   = (const float*)d_in[6];
    const float* W_lin   = (const float*)d_in[7];
    const float* b_lin   = (const float*)d_in[8];
    const float* W_ln    = (const float*)d_in[9];
    const float* b_ln    = (const float*)d_in[10];

    char* w = (char*)d_ws;
    float* h        = (float*)(w);                    // [16][2048][256] f32 (dead after scores_mh; reused for sh partials)
    float* lin      = (float*)(w + 33554432);
    float* h2       = (float*)(w + 37748736);
    float* E1p_mh   = (float*)(w + 41943040);
    float* E1n_mh   = (float*)(w + 42074112);
    float2* E2pn_mh = (float2*)(w + 42205184);
    float* E1p_sh   = (float*)(w + 42467328);
    float* E1n_sh   = (float*)(w + 42483712);
    float2* E2pn_sh = (float2*)(w + 42500096);
    unsigned long long* bits = (unsigned long long*)(w + 42532864);
    unsigned short* x_bf  = (unsigned short*)(w + 43581440);
    unsigned short* x2_bf = (unsigned short*)(w + 43581440);
    unsigned short* WhT   = (unsigned short*)(w + 49872896);
    unsigned short* WoT   = (unsigned short*)(w + 53018624);
    unsigned short* Wl_bf = (unsigned short*)(w + 54067200);
    unsigned short* Wn_bf = (unsigned short*)(w + 55115776);
    unsigned short* hT    = (unsigned short*)(w + 55246848);
    unsigned short* h2T   = (unsigned short*)(w + 72024064);
    unsigned short* x1_bf = (unsigned short*)(w + 74121216);
    float* pacc  = h;              // 8x[2][2048][256] f32 = 33.55 MB == h region
    float* plsum = E1p_mh;         // 8x[2][2048] f32 = 128 KB (E1p_mh dead by then)

    // 0) prep
    adjbits_kernel<<<(Bb * Nn * Nn) / 256, 256, 0, stream>>>(adj, bits);
    cast_bf_kernel<<<(Bb * Nn * Ff) / 1024, 256, 0, stream>>>(x, x_bf);
    cast_bf_kernel<<<(Oo * Hh * Oo) / 1024, 256, 0, stream>>>(W_lin, Wl_bf);
    cast_bf_kernel<<<(Oo * Oo) / 1024, 256, 0, stream>>>(W_ln, Wn_bf);
    transpose_bf_kernel<<<dim3(Oo / 32, Ff / 32, Hh), 256, 0, stream>>>(W_heads, WhT, Ff, Oo);
    transpose_bf_kernel<<<dim3(Oo / 32, (Hh * Oo) / 32, 1), 256, 0, stream>>>(W_out, WoT, Hh * Oo, Oo);

    // 1) h = x @ W_heads (+ hT bf16)
    gemm_bf_kernel<<<dim3(Nn / 64, 1, Bb * Hh), 256, 0, stream>>>(
        x_bf, Ff, (long long)Nn * Ff, 3, WhT, (long long)Ff * Oo, 7,
        h, (long long)Nn * Oo, hT, (long long)Nn * Oo, Nn, nullptr, 1);
    // 2) scores + exp factors (mh)
    scores_exp_kernel<<<(Bb * Hh * Nn) / 4, 256, 0, stream>>>(h, a_heads, E1p_mh, E1n_mh, E2pn_mh, Nn, Hh);
    // 3) multihead attention + elu -> x1_bf  (512-thread, slim B-prefetch)
    attn_v4_kernel<<<dim3(Bb * Hh, Nn / 64), 512, 0, stream>>>(
        hT, (const unsigned*)bits, E1p_mh, E1n_mh, E2pn_mh, x1_bf);
    // 4+5) fused: h2 = x1 @ W_out (+ h2T bf16) and lin = x1 @ W_lin^T
    gemm_dual_kernel<<<dim3(Nn / 64, 2, Bb), 256, 0, stream>>>(
        x1_bf, Hh * Oo, (long long)Nn * Hh * Oo, WoT, h2, h2T, lin);
    // 6) scores + exp factors (sh)
    scores_exp_kernel<<<(Bb * Nn) / 4, 256, 0, stream>>>(h2, a_out, E1p_sh, E1n_sh, E2pn_sh, Nn, 1);
    // 7) single-head attention, 8-way j-split partials (512 blocks -> 2/CU)
    attn_v2_kernel<256, 1, 0><<<dim3(Nn / 64, Bb, 8), 256, 0, stream>>>(
        h2T, (long long)Oo * Nn, (const unsigned*)bits, E1p_sh, E1n_sh, E2pn_sh,
        nullptr, 0, pacc, plsum, 0);
    // 8) combine -> x2_bf
    combine8_kernel<<<(Bb * Nn * 64) / 256, 256, 0, stream>>>(pacc, plsum, lin, b_lin, x2_bf);
    // 9) out = relu(x2 @ W_ln^T + b_ln)
    gemm_bf_kernel<<<dim3(Nn / 64, 1, Bb), 256, 0, stream>>>(
        x2_bf, Oo, (long long)Nn * Oo, 0, Wn_bf, 0, 0,
        (float*)d_out, (long long)Nn * Oo, nullptr, 0, Nn, b_ln, 2);
}

// Round 10
// 300.353 us; speedup vs baseline: 1.7229x; 1.2521x over previous
//
#include <hip/hip_runtime.h>
#include <hip/hip_bf16.h>

constexpr int Bb = 2, Nn = 2048, Ff = 768, Hh = 8, Oo = 256;

typedef __attribute__((ext_vector_type(8)))  short   short8;
typedef __attribute__((ext_vector_type(16))) float   f32x16;
typedef __attribute__((ext_vector_type(4)))  unsigned short ushort4_t;

__device__ inline unsigned short f2bf(float f) {
    unsigned u = __float_as_uint(f);
    u = (u + 0x7FFFu + ((u >> 16) & 1u)) >> 16;   // RNE
    return (unsigned short)u;
}

// ---------------- adjacency bitmask ----------------
__global__ __launch_bounds__(256) void adjbits_kernel(
        const float* __restrict__ adj, unsigned long long* __restrict__ bits) {
    size_t gid = (size_t)blockIdx.x * 256 + threadIdx.x;
    float v = adj[gid];
    unsigned long long m = __ballot(v > 0.f);
    if ((threadIdx.x & 63) == 0) bits[gid >> 6] = m;
}

// ---------------- f32 -> bf16 flat cast ----------------
__global__ __launch_bounds__(256) void cast_bf_kernel(
        const float* __restrict__ in, unsigned short* __restrict__ out) {
    size_t i = (size_t)blockIdx.x * 256 + threadIdx.x;
    float4 v = ((const float4*)in)[i];
    ushort4_t o;
    o.x = f2bf(v.x); o.y = f2bf(v.y); o.z = f2bf(v.z); o.w = f2bf(v.w);
    ((ushort4_t*)out)[i] = o;
}

// ======== B-fragment layout: frag id = nt32*(K/16)+kt, 1 KB each; ========
// ======== within frag: slot = kh*32 + (n&31) (16 B), u16 jl = k&7   ========

// frag prep from W [K][N] f32 (n-contiguous rows). 4 frags / 256-thr block.
__global__ __launch_bounds__(256) void wfrag_kn_kernel(
        const float* __restrict__ W, unsigned short* __restrict__ out,
        int K, int N, long long sW, long long sO) {
    W   += (size_t)blockIdx.y * sW;
    out += (size_t)blockIdx.y * sO;
    int t = threadIdx.x;
    int f = blockIdx.x * 4 + (t >> 6);
    int slot = t & 63, kh = slot >> 5, lm = slot & 31;
    int nfk = K >> 4;
    int nt = f / nfk, kt = f - nt * nfk;
    const float* wp = W + (size_t)(kt * 16 + kh * 8) * N + nt * 32 + lm;
    ushort4_t o0, o1;
    o0.x = f2bf(wp[0]);            o0.y = f2bf(wp[(size_t)N]);
    o0.z = f2bf(wp[2 * (size_t)N]); o0.w = f2bf(wp[3 * (size_t)N]);
    o1.x = f2bf(wp[4 * (size_t)N]); o1.y = f2bf(wp[5 * (size_t)N]);
    o1.z = f2bf(wp[6 * (size_t)N]); o1.w = f2bf(wp[7 * (size_t)N]);
    unsigned short* op = out + (size_t)f * 512 + slot * 8;
    *(ushort4_t*)op = o0;
    *(ushort4_t*)(op + 4) = o1;
}

// frag prep from W [N][K] f32 (k-contiguous rows, i.e. the B^T weights).
__global__ __launch_bounds__(256) void wfrag_nk_kernel(
        const float* __restrict__ W, unsigned short* __restrict__ out, int K) {
    int t = threadIdx.x;
    int f = blockIdx.x * 4 + (t >> 6);
    int slot = t & 63, kh = slot >> 5, lm = slot & 31;
    int nfk = K >> 4;
    int nt = f / nfk, kt = f - nt * nfk;
    const float* wp = W + (size_t)(nt * 32 + lm) * K + kt * 16 + kh * 8;
    float4 a = *(const float4*)wp, b = *(const float4*)(wp + 4);
    ushort4_t o0, o1;
    o0.x = f2bf(a.x); o0.y = f2bf(a.y); o0.z = f2bf(a.z); o0.w = f2bf(a.w);
    o1.x = f2bf(b.x); o1.y = f2bf(b.y); o1.z = f2bf(b.z); o1.w = f2bf(b.w);
    unsigned short* op = out + (size_t)f * 512 + slot * 8;
    *(ushort4_t*)op = o0;
    *(ushort4_t*)(op + 4) = o1;
}

// ---------------- MFMA GEMM: C[M x 256] = A[M x K] * B(frag layout) ----------------
// mode 0: fp32 C. mode 1: fp32 C + bf16 frag-layout CF. mode 2: bias+relu fp32 C.
__global__ __launch_bounds__(256) void gemm_bf_kernel(
        const unsigned short* __restrict__ A, int K, long long sA, int bAshift,
        const unsigned short* __restrict__ BF, long long sB, int bmask,
        float* __restrict__ C, long long sC,
        unsigned short* __restrict__ CF, long long sCF, int Mtot,
        const float* __restrict__ bias, int mode) {
    int z = blockIdx.z;
    A  += (size_t)(z >> bAshift) * sA;
    BF += (size_t)(z & bmask) * sB;
    C  += (size_t)z * sC;
    if (CF) CF += (size_t)z * sCF;
    int m0 = blockIdx.x * 64;
    int t = threadIdx.x;
    int wv = t >> 6, lane = t & 63;
    int lm = lane & 31, kh = lane >> 5;
    int nfk = K >> 4;
    __shared__ unsigned short As[64][40];
    f32x16 acc[2][2] = {};
    int sr = t >> 2, sc = (t & 3) * 8;
    const unsigned short* ag  = A + (size_t)(m0 + sr) * K + sc;
    const unsigned short* bg0 = BF + (size_t)(wv * 2) * nfk * 512;
    const unsigned short* bg1 = bg0 + (size_t)nfk * 512;
    for (int k0 = 0; k0 < K; k0 += 32) {
        *(short8*)&As[sr][sc] = *(const short8*)(ag + k0);
        int kt0 = k0 >> 4;
        __syncthreads();
#pragma unroll
        for (int s = 0; s < 2; ++s) {
            short8 a0 = *(const short8*)&As[lm][s * 16 + kh * 8];
            short8 a1 = *(const short8*)&As[32 + lm][s * 16 + kh * 8];
            short8 b0 = *(const short8*)(bg0 + (size_t)(kt0 + s) * 512 + lane * 8);
            short8 b1 = *(const short8*)(bg1 + (size_t)(kt0 + s) * 512 + lane * 8);
            acc[0][0] = __builtin_amdgcn_mfma_f32_32x32x16_bf16(a0, b0, acc[0][0], 0, 0, 0);
            acc[0][1] = __builtin_amdgcn_mfma_f32_32x32x16_bf16(a0, b1, acc[0][1], 0, 0, 0);
            acc[1][0] = __builtin_amdgcn_mfma_f32_32x32x16_bf16(a1, b0, acc[1][0], 0, 0, 0);
            acc[1][1] = __builtin_amdgcn_mfma_f32_32x32x16_bf16(a1, b1, acc[1][1], 0, 0, 0);
        }
        __syncthreads();
    }
#pragma unroll
    for (int mt = 0; mt < 2; ++mt)
#pragma unroll
        for (int nt = 0; nt < 2; ++nt) {
            int colg = wv * 64 + nt * 32 + lm;
            float bv = (mode == 2) ? bias[colg] : 0.f;
#pragma unroll
            for (int reg = 0; reg < 16; ++reg) {
                int rl = mt * 32 + 4 * kh + (reg & 3) + 8 * (reg >> 2);
                float v = acc[mt][nt][reg];
                if (mode == 2) { v += bv; v = fmaxf(v, 0.f); }
                C[(size_t)(m0 + rl) * 256 + colg] = v;
            }
            if (mode == 1) {
#pragma unroll
                for (int q = 0; q < 4; ++q) {
                    int kt = m0 / 16 + mt * 2 + (q >> 1);
                    size_t fi = ((size_t)(colg >> 5) * (Mtot / 16) + kt) * 512 +
                                ((q & 1) * 32 + (colg & 31)) * 8 + kh * 4;
                    ushort4_t pk;
                    pk.x = f2bf(acc[mt][nt][q * 4 + 0]);
                    pk.y = f2bf(acc[mt][nt][q * 4 + 1]);
                    pk.z = f2bf(acc[mt][nt][q * 4 + 2]);
                    pk.w = f2bf(acc[mt][nt][q * 4 + 3]);
                    *(ushort4_t*)(CF + fi) = pk;
                }
            }
        }
}

// ---------------- dual MFMA GEMM: x1 @ [WoF ; WlF] ----------------
__global__ __launch_bounds__(256) void gemm_dual_kernel(
        const unsigned short* __restrict__ A, int K, long long sA,
        const unsigned short* __restrict__ BF,
        float* __restrict__ h2, unsigned short* __restrict__ h2f,
        float* __restrict__ lin) {
    int b = blockIdx.z, ng = blockIdx.y;
    A += (size_t)b * sA;
    int nfk = K >> 4;                    // 128
    BF += (size_t)ng * 8 * nfk * 512;    // WlF adjacent after WoF
    int m0 = blockIdx.x * 64;
    int t = threadIdx.x;
    int wv = t >> 6, lane = t & 63;
    int lm = lane & 31, kh = lane >> 5;
    __shared__ unsigned short As[64][40];
    f32x16 acc[2][2] = {};
    int sr = t >> 2, sc = (t & 3) * 8;
    const unsigned short* ag  = A + (size_t)(m0 + sr) * K + sc;
    const unsigned short* bg0 = BF + (size_t)(wv * 2) * nfk * 512;
    const unsigned short* bg1 = bg0 + (size_t)nfk * 512;
    for (int k0 = 0; k0 < K; k0 += 32) {
        *(short8*)&As[sr][sc] = *(const short8*)(ag + k0);
        int kt0 = k0 >> 4;
        __syncthreads();
#pragma unroll
        for (int s = 0; s < 2; ++s) {
            short8 a0 = *(const short8*)&As[lm][s * 16 + kh * 8];
            short8 a1 = *(const short8*)&As[32 + lm][s * 16 + kh * 8];
            short8 b0 = *(const short8*)(bg0 + (size_t)(kt0 + s) * 512 + lane * 8);
            short8 b1 = *(const short8*)(bg1 + (size_t)(kt0 + s) * 512 + lane * 8);
            acc[0][0] = __builtin_amdgcn_mfma_f32_32x32x16_bf16(a0, b0, acc[0][0], 0, 0, 0);
            acc[0][1] = __builtin_amdgcn_mfma_f32_32x32x16_bf16(a0, b1, acc[0][1], 0, 0, 0);
            acc[1][0] = __builtin_amdgcn_mfma_f32_32x32x16_bf16(a1, b0, acc[1][0], 0, 0, 0);
            acc[1][1] = __builtin_amdgcn_mfma_f32_32x32x16_bf16(a1, b1, acc[1][1], 0, 0, 0);
        }
        __syncthreads();
    }
    float* C = (ng == 0 ? h2 : lin) + (size_t)b * Nn * 256;
    unsigned short* CF = h2f + (size_t)b * 524288;
#pragma unroll
    for (int mt = 0; mt < 2; ++mt)
#pragma unroll
        for (int nt = 0; nt < 2; ++nt) {
            int colg = wv * 64 + nt * 32 + lm;
#pragma unroll
            for (int reg = 0; reg < 16; ++reg) {
                int rl = mt * 32 + 4 * kh + (reg & 3) + 8 * (reg >> 2);
                C[(size_t)(m0 + rl) * 256 + colg] = acc[mt][nt][reg];
            }
            if (ng == 0) {
#pragma unroll
                for (int q = 0; q < 4; ++q) {
                    int kt = m0 / 16 + mt * 2 + (q >> 1);
                    size_t fi = ((size_t)(colg >> 5) * 128 + kt) * 512 +
                                ((q & 1) * 32 + (colg & 31)) * 8 + kh * 4;
                    ushort4_t pk;
                    pk.x = f2bf(acc[mt][nt][q * 4 + 0]);
                    pk.y = f2bf(acc[mt][nt][q * 4 + 1]);
                    pk.z = f2bf(acc[mt][nt][q * 4 + 2]);
                    pk.w = f2bf(acc[mt][nt][q * 4 + 3]);
                    *(ushort4_t*)(CF + fi) = pk;
                }
            }
        }
}

// ---------------- scores + exp factors ----------------
__global__ __launch_bounds__(256) void scores_exp_kernel(
        const float* __restrict__ h, const float* __restrict__ a,
        float* __restrict__ E1p, float* __restrict__ E1n,
        float2* __restrict__ E2pn, int NperH, int H) {
    int tid = threadIdx.x;
    int lane = tid & 63, wv = tid >> 6;
    long long row = (long long)blockIdx.x * 4 + wv;
    int head = (int)((row / NperH) % H);
    const float* ap = a + (size_t)head * 2 * Oo;
    float4 x4 = ((const float4*)(h + (size_t)row * Oo))[lane];
    float4 a1 = ((const float4*)ap)[lane];
    float4 a2 = ((const float4*)(ap + Oo))[lane];
    float t1 = x4.x * a1.x + x4.y * a1.y + x4.z * a1.z + x4.w * a1.w;
    float t2 = x4.x * a2.x + x4.y * a2.y + x4.z * a2.z + x4.w * a2.w;
    for (int off = 32; off; off >>= 1) {
        t1 += __shfl_down(t1, off, 64);
        t2 += __shfl_down(t2, off, 64);
    }
    if (!lane) {
        E1p[row] = __expf(t1);
        E1n[row] = __expf(0.2f * t1);
        E2pn[row] = make_float2(__expf(t2), __expf(0.2f * t2));
    }
}

// ---------------- pipelined MFMA attention, frag-layout B ----------------
// MODE 0: direct (elu, bf16 out). MODE 1: partial over j-range (f32 acc + l).
// SWAPXY 1: blockIdx.x = bh (XCD pin), blockIdx.y = it.
template<int JLEN, int MODE, int SWAPXY>
__global__ __launch_bounds__(256, 2) void attn_v5_kernel(
        const unsigned short* __restrict__ hfrag,
        const unsigned* __restrict__ bits,
        const float* __restrict__ E1p, const float* __restrict__ E1n,
        const float2* __restrict__ E2pn,
        unsigned short* __restrict__ outbf, int ldo,
        float* __restrict__ pacc, float* __restrict__ plsum,
        int hshift) {
    constexpr int W = JLEN / 32, NC = JLEN / 64, ABS = W + 1;
    int it = SWAPXY ? blockIdx.y : blockIdx.x;
    int bh = SWAPXY ? blockIdx.x : blockIdx.y;
    int js = blockIdx.z;
    int b = bh >> hshift, hd = bh & ((1 << hshift) - 1);
    int i0 = it * 64, jbase = js * JLEN;
    int kt0 = js * (JLEN / 16);
    int t = threadIdx.x, lane = t & 63;
    int wv = t >> 6, lm = lane & 31, kh = lane >> 5;
    int ti = lane, jq = wv;

    __shared__ unsigned ab[64 * ABS];
    __shared__ __align__(16) unsigned short ps[2][64][64];
    __shared__ float lred[64][5];
    __shared__ float linv[64];

    const unsigned* bb = bits + ((size_t)b * Nn + i0) * 64 + (jbase >> 5);
    for (int k = t; k < 64 * W; k += 256) {
        int r = k / W, w0 = k - r * W;
        ab[r * ABS + w0] = bb[(size_t)r * 64 + w0];
    }
    __syncthreads();   // ab[] must be visible before computeP

    float e1p = E1p[(size_t)bh * Nn + i0 + ti];
    float e1n = E1n[(size_t)bh * Nn + i0 + ti];
    const float4* e2base = (const float4*)(E2pn + (size_t)bh * Nn + jbase);

    const unsigned short* bg0 = hfrag + (size_t)bh * 524288 + (size_t)(wv * 2) * 128 * 512;
    const unsigned short* bg1 = bg0 + 128 * 512;

    f32x16 acc[2][2] = {};
    float lpart = 0.f;
    short8 B0[8], B1[8];

    auto loadB = [&](int c, short8* B) {
#pragma unroll
        for (int s = 0; s < 4; ++s) {
            int kt = kt0 + c * 4 + s;
            B[2 * s]     = *(const short8*)(bg0 + (size_t)kt * 512 + lane * 8);
            B[2 * s + 1] = *(const short8*)(bg1 + (size_t)kt * 512 + lane * 8);
        }
    };
    auto computeP = [&](int c, int buf) {
        int cj = c * 64;
        unsigned word = ab[ti * ABS + ((cj >> 5) + (jq >> 1))];
        unsigned field = word >> ((jq & 1) * 16);
        const float4* ep = e2base + ((cj + jq * 16) >> 1);
        unsigned pk[8];
#pragma unroll
        for (int u = 0; u < 8; ++u) {
            float4 q = ep[u];
            float pp0 = e1p * q.x, pn0 = e1n * q.y;
            float p0 = pp0 > 1.f ? pp0 : pn0;
            p0 = ((field >> (2 * u)) & 1u) ? p0 : 0.f;
            float pp1 = e1p * q.z, pn1 = e1n * q.w;
            float p1 = pp1 > 1.f ? pp1 : pn1;
            p1 = ((field >> (2 * u + 1)) & 1u) ? p1 : 0.f;
            lpart += p0 + p1;
            __hip_bfloat162 hv = __float22bfloat162_rn(make_float2(p0, p1));
            pk[u] = *(unsigned*)&hv;
        }
        unsigned sw = ti & 7;
        uint4 v0; v0.x = pk[0]; v0.y = pk[1]; v0.z = pk[2]; v0.w = pk[3];
        uint4 v1; v1.x = pk[4]; v1.y = pk[5]; v1.z = pk[6]; v1.w = pk[7];
        *(uint4*)&ps[buf][ti][((2 * jq) ^ sw) * 8]     = v0;
        *(uint4*)&ps[buf][ti][((2 * jq + 1) ^ sw) * 8] = v1;
    };
    auto mfmaStep = [&](int buf, short8* B) {
        unsigned sw = lm & 7;
#pragma unroll
        for (int s = 0; s < 4; ++s) {
            short8 a0 = *(const short8*)&ps[buf][lm][((2 * s + kh) ^ sw) * 8];
            short8 a1 = *(const short8*)&ps[buf][32 + lm][((2 * s + kh) ^ sw) * 8];
            acc[0][0] = __builtin_amdgcn_mfma_f32_32x32x16_bf16(a0, B[2 * s],     acc[0][0], 0, 0, 0);
            acc[0][1] = __builtin_amdgcn_mfma_f32_32x32x16_bf16(a0, B[2 * s + 1], acc[0][1], 0, 0, 0);
            acc[1][0] = __builtin_amdgcn_mfma_f32_32x32x16_bf16(a1, B[2 * s],     acc[1][0], 0, 0, 0);
            acc[1][1] = __builtin_amdgcn_mfma_f32_32x32x16_bf16(a1, B[2 * s + 1], acc[1][1], 0, 0, 0);
        }
    };

    loadB(0, B0);
    computeP(0, 0);
    __syncthreads();
    for (int c = 0; c < NC; c += 2) {
        loadB(c + 1, B1);
        mfmaStep(0, B0);
        computeP(c + 1, 1);
        __syncthreads();
        if (c + 2 < NC) loadB(c + 2, B0);
        mfmaStep(1, B1);
        if (c + 2 < NC) computeP(c + 2, 0);
        __syncthreads();
    }

    lred[ti][jq] = lpart;
    __syncthreads();
    if (MODE == 0) {
        if (t < 64) linv[t] = 1.f / (lred[t][0] + lred[t][1] + lred[t][2] + lred[t][3]);
        __syncthreads();
#pragma unroll
        for (int mt = 0; mt < 2; ++mt)
#pragma unroll
            for (int nt = 0; nt < 2; ++nt) {
                int o = wv * 64 + nt * 32 + lm;
#pragma unroll
                for (int reg = 0; reg < 16; ++reg) {
                    int rl = mt * 32 + 4 * kh + (reg & 3) + 8 * (reg >> 2);
                    float v = acc[mt][nt][reg] * linv[rl];
                    v = v > 0.f ? v : expm1f(v);   // elu (layer 1)
                    outbf[((size_t)b * Nn + i0 + rl) * ldo + (size_t)hd * Oo + o] = f2bf(v);
                }
            }
    } else {
        if (t < 64)
            plsum[((size_t)js * Bb + b) * Nn + i0 + t] =
                lred[t][0] + lred[t][1] + lred[t][2] + lred[t][3];
        float* pa = pacc + (((size_t)js * Bb + b) * Nn) * 256;
#pragma unroll
        for (int mt = 0; mt < 2; ++mt)
#pragma unroll
            for (int nt = 0; nt < 2; ++nt) {
                int o = wv * 64 + nt * 32 + lm;
#pragma unroll
                for (int reg = 0; reg < 16; ++reg) {
                    int rl = mt * 32 + 4 * kh + (reg & 3) + 8 * (reg >> 2);
                    pa[(size_t)(i0 + rl) * 256 + o] = acc[mt][nt][reg];
                }
            }
    }
}

// ---------------- combine 8 partials: x2 = Σacc/Σl + lin + b ----------------
__global__ __launch_bounds__(256) void combine8_kernel(
        const float* __restrict__ pacc, const float* __restrict__ plsum,
        const float* __restrict__ lin, const float* __restrict__ bias,
        unsigned short* __restrict__ out) {
    int gid = blockIdx.x * 256 + threadIdx.x;
    int row = gid >> 6;
    int o4 = gid & 63;
    size_t ps4 = (size_t)Bb * Nn * 64;
    const float4* p = (const float4*)pacc + (size_t)row * 64 + o4;
    float4 s = p[0];
#pragma unroll
    for (int k = 1; k < 8; ++k) {
        float4 q = p[k * ps4];
        s.x += q.x; s.y += q.y; s.z += q.z; s.w += q.w;
    }
    int BN = Bb * Nn;
    float lsum = 0.f;
#pragma unroll
    for (int k = 0; k < 8; ++k) lsum += plsum[row + k * BN];
    float li = 1.f / lsum;
    float4 lv = ((const float4*)lin)[(size_t)row * 64 + o4];
    float4 bv = ((const float4*)bias)[o4];
    float4 v;
    v.x = s.x * li + lv.x + bv.x; v.y = s.y * li + lv.y + bv.y;
    v.z = s.z * li + lv.z + bv.z; v.w = s.w * li + lv.w + bv.w;
    __hip_bfloat162 h0 = __float22bfloat162_rn(make_float2(v.x, v.y));
    __hip_bfloat162 h1 = __float22bfloat162_rn(make_float2(v.z, v.w));
    uint2 st; st.x = *(unsigned*)&h0; st.y = *(unsigned*)&h1;
    *(uint2*)(out + (size_t)gid * 4) = st;
}

extern "C" void kernel_launch(void* const* d_in, const int* in_sizes, int n_in,
                              void* d_out, int out_size, void* d_ws, size_t ws_size,
                              hipStream_t stream) {
    const float* x       = (const float*)d_in[0];
    const float* adj     = (const float*)d_in[1];
    const float* W_heads = (const float*)d_in[3];
    const float* a_heads = (const float*)d_in[4];
    const float* W_out   = (const float*)d_in[5];
    const float* a_out   = (const float*)d_in[6];
    const float* W_lin   = (const float*)d_in[7];
    const float* b_lin   = (const float*)d_in[8];
    const float* W_ln    = (const float*)d_in[9];
    const float* b_ln    = (const float*)d_in[10];

    char* w = (char*)d_ws;
    float* h        = (float*)(w);                    // [16][2048][256] f32 (dead after scores; reused for sh partials)
    float* lin      = (float*)(w + 33554432);
    float* h2       = (float*)(w + 37748736);
    float* E1p_mh   = (float*)(w + 41943040);
    float* E1n_mh   = (float*)(w + 42074112);
    float2* E2pn_mh = (float2*)(w + 42205184);
    float* E1p_sh   = (float*)(w + 42467328);
    float* E1n_sh   = (float*)(w + 42483712);
    float2* E2pn_sh = (float2*)(w + 42500096);
    unsigned long long* bits = (unsigned long long*)(w + 42532864);   // 1 MB
    unsigned short* x_bf  = (unsigned short*)(w + 43581440);   // [2][2048][768]
    unsigned short* x2_bf = (unsigned short*)(w + 43581440);   // reuse after gemm1
    unsigned short* WhF   = (unsigned short*)(w + 49872896);   // 8 x 384 KB frag
    unsigned short* WoF   = (unsigned short*)(w + 53018624);   // 1 MB frag }adjacent
    unsigned short* WlF   = (unsigned short*)(w + 54067200);   // 1 MB frag }
    unsigned short* WnF   = (unsigned short*)(w + 55115776);   // 128 KB frag
    unsigned short* hfrag = (unsigned short*)(w + 55246848);   // 16 MB
    unsigned short* h2frag= (unsigned short*)(w + 72024064);   // 2 MB
    unsigned short* x1_bf = (unsigned short*)(w + 74121216);   // [2][2048][2048]
    float* pacc  = h;              // 8x 4 MB = 32 MB == h region
    float* plsum = E1p_mh;         // 128 KB (E1p_mh dead by then)

    // 0) prep: bitmask, x cast, weight frag tables
    adjbits_kernel<<<(Bb * Nn * Nn) / 256, 256, 0, stream>>>(adj, bits);
    cast_bf_kernel<<<(Bb * Nn * Ff) / 1024, 256, 0, stream>>>(x, x_bf);
    wfrag_kn_kernel<<<dim3(96, Hh), 256, 0, stream>>>(
        W_heads, WhF, Ff, Oo, (long long)Ff * Oo, 384LL * 512);
    wfrag_kn_kernel<<<dim3(256, 1), 256, 0, stream>>>(
        W_out, WoF, Hh * Oo, Oo, 0, 0);
    wfrag_nk_kernel<<<256, 256, 0, stream>>>(W_lin, WlF, Hh * Oo);
    wfrag_nk_kernel<<<32, 256, 0, stream>>>(W_ln, WnF, Oo);

    // 1) h = x @ W_heads (f32 h + hfrag)
    gemm_bf_kernel<<<dim3(Nn / 64, 1, Bb * Hh), 256, 0, stream>>>(
        x_bf, Ff, (long long)Nn * Ff, 3, WhF, 384LL * 512, 7,
        h, (long long)Nn * Oo, hfrag, 524288, Nn, nullptr, 1);
    // 2) scores + exp factors (mh)
    scores_exp_kernel<<<(Bb * Hh * Nn) / 4, 256, 0, stream>>>(h, a_heads, E1p_mh, E1n_mh, E2pn_mh, Nn, Hh);
    // 3) multihead attention + elu -> x1_bf  (bh-major grid: XCD = bh%8)
    attn_v5_kernel<2048, 0, 1><<<dim3(Bb * Hh, Nn / 64, 1), 256, 0, stream>>>(
        hfrag, (const unsigned*)bits, E1p_mh, E1n_mh, E2pn_mh,
        x1_bf, Hh * Oo, nullptr, nullptr, 3);
    // 4+5) fused: h2 = x1 @ W_out (+ h2frag) and lin = x1 @ W_lin^T
    gemm_dual_kernel<<<dim3(Nn / 64, 2, Bb), 256, 0, stream>>>(
        x1_bf, Hh * Oo, (long long)Nn * Hh * Oo, WoF, h2, h2frag, lin);
    // 6) scores + exp factors (sh)
    scores_exp_kernel<<<(Bb * Nn) / 4, 256, 0, stream>>>(h2, a_out, E1p_sh, E1n_sh, E2pn_sh, Nn, 1);
    // 7) single-head attention, 8-way j-split partials
    attn_v5_kernel<256, 1, 0><<<dim3(Nn / 64, Bb, 8), 256, 0, stream>>>(
        h2frag, (const unsigned*)bits, E1p_sh, E1n_sh, E2pn_sh,
        nullptr, 0, pacc, plsum, 0);
    // 8) combine -> x2_bf
    combine8_kernel<<<(Bb * Nn * 64) / 256, 256, 0, stream>>>(pacc, plsum, lin, b_lin, x2_bf);
    // 9) out = relu(x2 @ W_ln^T + b_ln)
    gemm_bf_kernel<<<dim3(Nn / 64, 1, Bb), 256, 0, stream>>>(
        x2_bf, Oo, (long long)Nn * Oo, 0, WnF, 0, 0,
        (float*)d_out, (long long)Nn * Oo, nullptr, 0, Nn, b_ln, 2);
}

// Round 11
// 297.131 us; speedup vs baseline: 1.7416x; 1.0108x over previous
//
#include <hip/hip_runtime.h>
#include <hip/hip_bf16.h>

constexpr int Bb = 2, Nn = 2048, Ff = 768, Hh = 8, Oo = 256;

typedef __attribute__((ext_vector_type(8)))  short   short8;
typedef __attribute__((ext_vector_type(16))) float   f32x16;
typedef __attribute__((ext_vector_type(4)))  unsigned short ushort4_t;

__device__ inline unsigned short f2bf(float f) {
    unsigned u = __float_as_uint(f);
    u = (u + 0x7FFFu + ((u >> 16) & 1u)) >> 16;   // RNE
    return (unsigned short)u;
}

// ---------------- adjacency bitmask ----------------
__global__ __launch_bounds__(256) void adjbits_kernel(
        const float* __restrict__ adj, unsigned long long* __restrict__ bits) {
    size_t gid = (size_t)blockIdx.x * 256 + threadIdx.x;
    float v = adj[gid];
    unsigned long long m = __ballot(v > 0.f);
    if ((threadIdx.x & 63) == 0) bits[gid >> 6] = m;
}

// ---------------- f32 -> bf16 flat cast ----------------
__global__ __launch_bounds__(256) void cast_bf_kernel(
        const float* __restrict__ in, unsigned short* __restrict__ out) {
    size_t i = (size_t)blockIdx.x * 256 + threadIdx.x;
    float4 v = ((const float4*)in)[i];
    ushort4_t o;
    o.x = f2bf(v.x); o.y = f2bf(v.y); o.z = f2bf(v.z); o.w = f2bf(v.w);
    ((ushort4_t*)out)[i] = o;
}

// ======== B-fragment layout: frag id = nt32*(K/16)+kt, 1 KB each ========
__global__ __launch_bounds__(256) void wfrag_kn_kernel(
        const float* __restrict__ W, unsigned short* __restrict__ out,
        int K, int N, long long sW, long long sO) {
    W   += (size_t)blockIdx.y * sW;
    out += (size_t)blockIdx.y * sO;
    int t = threadIdx.x;
    int f = blockIdx.x * 4 + (t >> 6);
    int slot = t & 63, kh = slot >> 5, lm = slot & 31;
    int nfk = K >> 4;
    int nt = f / nfk, kt = f - nt * nfk;
    const float* wp = W + (size_t)(kt * 16 + kh * 8) * N + nt * 32 + lm;
    ushort4_t o0, o1;
    o0.x = f2bf(wp[0]);             o0.y = f2bf(wp[(size_t)N]);
    o0.z = f2bf(wp[2 * (size_t)N]); o0.w = f2bf(wp[3 * (size_t)N]);
    o1.x = f2bf(wp[4 * (size_t)N]); o1.y = f2bf(wp[5 * (size_t)N]);
    o1.z = f2bf(wp[6 * (size_t)N]); o1.w = f2bf(wp[7 * (size_t)N]);
    unsigned short* op = out + (size_t)f * 512 + slot * 8;
    *(ushort4_t*)op = o0;
    *(ushort4_t*)(op + 4) = o1;
}

__global__ __launch_bounds__(256) void wfrag_nk_kernel(
        const float* __restrict__ W, unsigned short* __restrict__ out, int K) {
    int t = threadIdx.x;
    int f = blockIdx.x * 4 + (t >> 6);
    int slot = t & 63, kh = slot >> 5, lm = slot & 31;
    int nfk = K >> 4;
    int nt = f / nfk, kt = f - nt * nfk;
    const float* wp = W + (size_t)(nt * 32 + lm) * K + kt * 16 + kh * 8;
    float4 a = *(const float4*)wp, b = *(const float4*)(wp + 4);
    ushort4_t o0, o1;
    o0.x = f2bf(a.x); o0.y = f2bf(a.y); o0.z = f2bf(a.z); o0.w = f2bf(a.w);
    o1.x = f2bf(b.x); o1.y = f2bf(b.y); o1.z = f2bf(b.z); o1.w = f2bf(b.w);
    unsigned short* op = out + (size_t)f * 512 + slot * 8;
    *(ushort4_t*)op = o0;
    *(ushort4_t*)(op + 4) = o1;
}

// ---------------- MFMA GEMM with optional fused scores+exp epilogue ----------------
// mode 1: bf16 frag CF (+ optional f32 C) + scores (aall != null): writes E1p/E1n/E2pn.
// mode 2: bias+relu f32 C.
__global__ __launch_bounds__(256) void gemm_bf_kernel(
        const unsigned short* __restrict__ A, int K, long long sA, int bAshift,
        const unsigned short* __restrict__ BF, long long sB, int bmask,
        float* __restrict__ C, long long sC,
        unsigned short* __restrict__ CF, long long sCF, int Mtot,
        const float* __restrict__ bias, int mode,
        const float* __restrict__ aall, int amask,
        float* __restrict__ E1p, float* __restrict__ E1n, float2* __restrict__ E2pn) {
    int z = blockIdx.z;
    A  += (size_t)(z >> bAshift) * sA;
    BF += (size_t)(z & bmask) * sB;
    if (C) C += (size_t)z * sC;
    if (CF) CF += (size_t)z * sCF;
    int m0 = blockIdx.x * 64;
    int t = threadIdx.x;
    int wv = t >> 6, lane = t & 63;
    int lm = lane & 31, kh = lane >> 5;
    int nfk = K >> 4;
    __shared__ __align__(16) unsigned short As[64][40];
    f32x16 acc[2][2] = {};
    int sr = t >> 2, sc = (t & 3) * 8;
    const unsigned short* ag  = A + (size_t)(m0 + sr) * K + sc;
    const unsigned short* bg0 = BF + (size_t)(wv * 2) * nfk * 512;
    const unsigned short* bg1 = bg0 + (size_t)nfk * 512;
    for (int k0 = 0; k0 < K; k0 += 32) {
        *(short8*)&As[sr][sc] = *(const short8*)(ag + k0);
        int kt0 = k0 >> 4;
        __syncthreads();
#pragma unroll
        for (int s = 0; s < 2; ++s) {
            short8 a0 = *(const short8*)&As[lm][s * 16 + kh * 8];
            short8 a1 = *(const short8*)&As[32 + lm][s * 16 + kh * 8];
            short8 b0 = *(const short8*)(bg0 + (size_t)(kt0 + s) * 512 + lane * 8);
            short8 b1 = *(const short8*)(bg1 + (size_t)(kt0 + s) * 512 + lane * 8);
            acc[0][0] = __builtin_amdgcn_mfma_f32_32x32x16_bf16(a0, b0, acc[0][0], 0, 0, 0);
            acc[0][1] = __builtin_amdgcn_mfma_f32_32x32x16_bf16(a0, b1, acc[0][1], 0, 0, 0);
            acc[1][0] = __builtin_amdgcn_mfma_f32_32x32x16_bf16(a1, b0, acc[1][0], 0, 0, 0);
            acc[1][1] = __builtin_amdgcn_mfma_f32_32x32x16_bf16(a1, b1, acc[1][1], 0, 0, 0);
        }
        __syncthreads();
    }
#pragma unroll
    for (int mt = 0; mt < 2; ++mt)
#pragma unroll
        for (int nt = 0; nt < 2; ++nt) {
            int colg = wv * 64 + nt * 32 + lm;
            float bv = (mode == 2) ? bias[colg] : 0.f;
            if (C) {
#pragma unroll
                for (int reg = 0; reg < 16; ++reg) {
                    int rl = mt * 32 + 4 * kh + (reg & 3) + 8 * (reg >> 2);
                    float v = acc[mt][nt][reg];
                    if (mode == 2) { v += bv; v = fmaxf(v, 0.f); }
                    C[(size_t)(m0 + rl) * 256 + colg] = v;
                }
            }
            if (mode == 1) {
#pragma unroll
                for (int q = 0; q < 4; ++q) {
                    int kt = m0 / 16 + mt * 2 + (q >> 1);
                    size_t fi = ((size_t)(colg >> 5) * (Mtot / 16) + kt) * 512 +
                                ((q & 1) * 32 + (colg & 31)) * 8 + kh * 4;
                    ushort4_t pk;
                    pk.x = f2bf(acc[mt][nt][q * 4 + 0]);
                    pk.y = f2bf(acc[mt][nt][q * 4 + 1]);
                    pk.z = f2bf(acc[mt][nt][q * 4 + 2]);
                    pk.w = f2bf(acc[mt][nt][q * 4 + 3]);
                    *(ushort4_t*)(CF + fi) = pk;
                }
            }
        }
    // ---- fused scores: s1/s2 dots from acc, butterfly over lm, exp, store ----
    if (aall) {
        const float* av = aall + (size_t)(z & amask) * 512;
        float a1v0 = av[wv * 64 + lm],       a1v1 = av[wv * 64 + 32 + lm];
        float a2v0 = av[256 + wv * 64 + lm], a2v1 = av[256 + wv * 64 + 32 + lm];
        float* sbuf = (float*)As;   // dead after K-loop; [row][8]: 0..3=s1 wv, 4..7=s2 wv
#pragma unroll
        for (int mt = 0; mt < 2; ++mt)
#pragma unroll
            for (int reg = 0; reg < 16; ++reg) {
                int rl = mt * 32 + 4 * kh + (reg & 3) + 8 * (reg >> 2);
                float v1 = acc[mt][0][reg] * a1v0 + acc[mt][1][reg] * a1v1;
                float v2 = acc[mt][0][reg] * a2v0 + acc[mt][1][reg] * a2v1;
#pragma unroll
                for (int m = 1; m <= 16; m <<= 1) {
                    v1 += __shfl_xor(v1, m, 64);
                    v2 += __shfl_xor(v2, m, 64);
                }
                if (lm == 0) { sbuf[rl * 8 + wv] = v1; sbuf[rl * 8 + 4 + wv] = v2; }
            }
        __syncthreads();
        if (t < 64) {
            float s1 = sbuf[t * 8] + sbuf[t * 8 + 1] + sbuf[t * 8 + 2] + sbuf[t * 8 + 3];
            float s2 = sbuf[t * 8 + 4] + sbuf[t * 8 + 5] + sbuf[t * 8 + 6] + sbuf[t * 8 + 7];
            size_t ei = (size_t)z * Nn + m0 + t;
            E1p[ei] = __expf(s1);
            E1n[ei] = __expf(0.2f * s1);
            E2pn[ei] = make_float2(__expf(s2), __expf(0.2f * s2));
        }
    }
}

// ---------------- dual MFMA GEMM: x1 @ [WoF ; WlF]; ng0 also fused sh scores ----------------
__global__ __launch_bounds__(256) void gemm_dual_kernel(
        const unsigned short* __restrict__ A, int K, long long sA,
        const unsigned short* __restrict__ BF,
        unsigned short* __restrict__ h2f, float* __restrict__ lin,
        const float* __restrict__ a_out,
        float* __restrict__ E1p, float* __restrict__ E1n, float2* __restrict__ E2pn) {
    int b = blockIdx.z, ng = blockIdx.y;
    A += (size_t)b * sA;
    int nfk = K >> 4;                    // 128
    BF += (size_t)ng * 8 * nfk * 512;
    int m0 = blockIdx.x * 64;
    int t = threadIdx.x;
    int wv = t >> 6, lane = t & 63;
    int lm = lane & 31, kh = lane >> 5;
    __shared__ __align__(16) unsigned short As[64][40];
    f32x16 acc[2][2] = {};
    int sr = t >> 2, sc = (t & 3) * 8;
    const unsigned short* ag  = A + (size_t)(m0 + sr) * K + sc;
    const unsigned short* bg0 = BF + (size_t)(wv * 2) * nfk * 512;
    const unsigned short* bg1 = bg0 + (size_t)nfk * 512;
    for (int k0 = 0; k0 < K; k0 += 32) {
        *(short8*)&As[sr][sc] = *(const short8*)(ag + k0);
        int kt0 = k0 >> 4;
        __syncthreads();
#pragma unroll
        for (int s = 0; s < 2; ++s) {
            short8 a0 = *(const short8*)&As[lm][s * 16 + kh * 8];
            short8 a1 = *(const short8*)&As[32 + lm][s * 16 + kh * 8];
            short8 b0 = *(const short8*)(bg0 + (size_t)(kt0 + s) * 512 + lane * 8);
            short8 b1 = *(const short8*)(bg1 + (size_t)(kt0 + s) * 512 + lane * 8);
            acc[0][0] = __builtin_amdgcn_mfma_f32_32x32x16_bf16(a0, b0, acc[0][0], 0, 0, 0);
            acc[0][1] = __builtin_amdgcn_mfma_f32_32x32x16_bf16(a0, b1, acc[0][1], 0, 0, 0);
            acc[1][0] = __builtin_amdgcn_mfma_f32_32x32x16_bf16(a1, b0, acc[1][0], 0, 0, 0);
            acc[1][1] = __builtin_amdgcn_mfma_f32_32x32x16_bf16(a1, b1, acc[1][1], 0, 0, 0);
        }
        __syncthreads();
    }
    if (ng == 1) {
        float* C = lin + (size_t)b * Nn * 256;
#pragma unroll
        for (int mt = 0; mt < 2; ++mt)
#pragma unroll
            for (int nt = 0; nt < 2; ++nt) {
                int colg = wv * 64 + nt * 32 + lm;
#pragma unroll
                for (int reg = 0; reg < 16; ++reg) {
                    int rl = mt * 32 + 4 * kh + (reg & 3) + 8 * (reg >> 2);
                    C[(size_t)(m0 + rl) * 256 + colg] = acc[mt][nt][reg];
                }
            }
    } else {
        unsigned short* CF = h2f + (size_t)b * 524288;
#pragma unroll
        for (int mt = 0; mt < 2; ++mt)
#pragma unroll
            for (int nt = 0; nt < 2; ++nt) {
                int colg = wv * 64 + nt * 32 + lm;
#pragma unroll
                for (int q = 0; q < 4; ++q) {
                    int kt = m0 / 16 + mt * 2 + (q >> 1);
                    size_t fi = ((size_t)(colg >> 5) * 128 + kt) * 512 +
                                ((q & 1) * 32 + (colg & 31)) * 8 + kh * 4;
                    ushort4_t pk;
                    pk.x = f2bf(acc[mt][nt][q * 4 + 0]);
                    pk.y = f2bf(acc[mt][nt][q * 4 + 1]);
                    pk.z = f2bf(acc[mt][nt][q * 4 + 2]);
                    pk.w = f2bf(acc[mt][nt][q * 4 + 3]);
                    *(ushort4_t*)(CF + fi) = pk;
                }
            }
        // fused sh scores
        float a1v0 = a_out[wv * 64 + lm],       a1v1 = a_out[wv * 64 + 32 + lm];
        float a2v0 = a_out[256 + wv * 64 + lm], a2v1 = a_out[256 + wv * 64 + 32 + lm];
        float* sbuf = (float*)As;
#pragma unroll
        for (int mt = 0; mt < 2; ++mt)
#pragma unroll
            for (int reg = 0; reg < 16; ++reg) {
                int rl = mt * 32 + 4 * kh + (reg & 3) + 8 * (reg >> 2);
                float v1 = acc[mt][0][reg] * a1v0 + acc[mt][1][reg] * a1v1;
                float v2 = acc[mt][0][reg] * a2v0 + acc[mt][1][reg] * a2v1;
#pragma unroll
                for (int m = 1; m <= 16; m <<= 1) {
                    v1 += __shfl_xor(v1, m, 64);
                    v2 += __shfl_xor(v2, m, 64);
                }
                if (lm == 0) { sbuf[rl * 8 + wv] = v1; sbuf[rl * 8 + 4 + wv] = v2; }
            }
        __syncthreads();
        if (t < 64) {
            float s1 = sbuf[t * 8] + sbuf[t * 8 + 1] + sbuf[t * 8 + 2] + sbuf[t * 8 + 3];
            float s2 = sbuf[t * 8 + 4] + sbuf[t * 8 + 5] + sbuf[t * 8 + 6] + sbuf[t * 8 + 7];
            size_t ei = (size_t)b * Nn + m0 + t;
            E1p[ei] = __expf(s1);
            E1n[ei] = __expf(0.2f * s1);
            E2pn[ei] = make_float2(__expf(s2), __expf(0.2f * s2));
        }
    }
}

// ---------------- pipelined MFMA attention, frag-layout B, max-trick P ----------------
template<int JLEN, int MODE, int SWAPXY>
__global__ __launch_bounds__(256, 2) void attn_v5_kernel(
        const unsigned short* __restrict__ hfrag,
        const unsigned* __restrict__ bits,
        const float* __restrict__ E1p, const float* __restrict__ E1n,
        const float2* __restrict__ E2pn,
        unsigned short* __restrict__ outbf, int ldo,
        float* __restrict__ pacc, float* __restrict__ plsum,
        int hshift) {
    constexpr int W = JLEN / 32, NC = JLEN / 64, ABS = W + 1;
    int it = SWAPXY ? blockIdx.y : blockIdx.x;
    int bh = SWAPXY ? blockIdx.x : blockIdx.y;
    int js = blockIdx.z;
    int b = bh >> hshift, hd = bh & ((1 << hshift) - 1);
    int i0 = it * 64, jbase = js * JLEN;
    int kt0 = js * (JLEN / 16);
    int t = threadIdx.x, lane = t & 63;
    int wv = t >> 6, lm = lane & 31, kh = lane >> 5;
    int ti = lane, jq = wv;

    __shared__ unsigned ab[64 * ABS];
    __shared__ __align__(16) unsigned short ps[2][64][64];
    __shared__ float lred[64][5];
    __shared__ float linv[64];

    const unsigned* bb = bits + ((size_t)b * Nn + i0) * 64 + (jbase >> 5);
    for (int k = t; k < 64 * W; k += 256) {
        int r = k / W, w0 = k - r * W;
        ab[r * ABS + w0] = bb[(size_t)r * 64 + w0];
    }
    __syncthreads();   // ab[] must be visible before computeP

    float e1p = E1p[(size_t)bh * Nn + i0 + ti];
    float e1n = E1n[(size_t)bh * Nn + i0 + ti];
    const float4* e2base = (const float4*)(E2pn + (size_t)bh * Nn + jbase);

    const unsigned short* bg0 = hfrag + (size_t)bh * 524288 + (size_t)(wv * 2) * 128 * 512;
    const unsigned short* bg1 = bg0 + 128 * 512;

    f32x16 acc[2][2] = {};
    float lpart = 0.f;
    short8 B0[8], B1[8];

    auto loadB = [&](int c, short8* B) {
#pragma unroll
        for (int s = 0; s < 4; ++s) {
            int kt = kt0 + c * 4 + s;
            B[2 * s]     = *(const short8*)(bg0 + (size_t)kt * 512 + lane * 8);
            B[2 * s + 1] = *(const short8*)(bg1 + (size_t)kt * 512 + lane * 8);
        }
    };
    auto computeP = [&](int c, int buf) {
        int cj = c * 64;
        unsigned word = ab[ti * ABS + ((cj >> 5) + (jq >> 1))];
        unsigned field = word >> ((jq & 1) * 16);
        const float4* ep = e2base + ((cj + jq * 16) >> 1);
        unsigned pk[8];
#pragma unroll
        for (int u = 0; u < 8; ++u) {
            float4 q = ep[u];
            // exp(s)>exp(0.2s) iff s>0  =>  select == max (exact)
            float p0 = fmaxf(e1p * q.x, e1n * q.y);
            p0 = ((field >> (2 * u)) & 1u) ? p0 : 0.f;
            float p1 = fmaxf(e1p * q.z, e1n * q.w);
            p1 = ((field >> (2 * u + 1)) & 1u) ? p1 : 0.f;
            lpart += p0 + p1;
            __hip_bfloat162 hv = __float22bfloat162_rn(make_float2(p0, p1));
            pk[u] = *(unsigned*)&hv;
        }
        unsigned sw = ti & 7;
        uint4 v0; v0.x = pk[0]; v0.y = pk[1]; v0.z = pk[2]; v0.w = pk[3];
        uint4 v1; v1.x = pk[4]; v1.y = pk[5]; v1.z = pk[6]; v1.w = pk[7];
        *(uint4*)&ps[buf][ti][((2 * jq) ^ sw) * 8]     = v0;
        *(uint4*)&ps[buf][ti][((2 * jq + 1) ^ sw) * 8] = v1;
    };
    auto mfmaStep = [&](int buf, short8* B) {
        unsigned sw = lm & 7;
#pragma unroll
        for (int s = 0; s < 4; ++s) {
            short8 a0 = *(const short8*)&ps[buf][lm][((2 * s + kh) ^ sw) * 8];
            short8 a1 = *(const short8*)&ps[buf][32 + lm][((2 * s + kh) ^ sw) * 8];
            acc[0][0] = __builtin_amdgcn_mfma_f32_32x32x16_bf16(a0, B[2 * s],     acc[0][0], 0, 0, 0);
            acc[0][1] = __builtin_amdgcn_mfma_f32_32x32x16_bf16(a0, B[2 * s + 1], acc[0][1], 0, 0, 0);
            acc[1][0] = __builtin_amdgcn_mfma_f32_32x32x16_bf16(a1, B[2 * s],     acc[1][0], 0, 0, 0);
            acc[1][1] = __builtin_amdgcn_mfma_f32_32x32x16_bf16(a1, B[2 * s + 1], acc[1][1], 0, 0, 0);
        }
    };

    loadB(0, B0);
    computeP(0, 0);
    __syncthreads();
    for (int c = 0; c < NC; c += 2) {
        loadB(c + 1, B1);
        mfmaStep(0, B0);
        computeP(c + 1, 1);
        __syncthreads();
        if (c + 2 < NC) loadB(c + 2, B0);
        mfmaStep(1, B1);
        if (c + 2 < NC) computeP(c + 2, 0);
        __syncthreads();
    }

    lred[ti][jq] = lpart;
    __syncthreads();
    if (MODE == 0) {
        if (t < 64) linv[t] = 1.f / (lred[t][0] + lred[t][1] + lred[t][2] + lred[t][3]);
        __syncthreads();
#pragma unroll
        for (int mt = 0; mt < 2; ++mt)
#pragma unroll
            for (int nt = 0; nt < 2; ++nt) {
                int o = wv * 64 + nt * 32 + lm;
#pragma unroll
                for (int reg = 0; reg < 16; ++reg) {
                    int rl = mt * 32 + 4 * kh + (reg & 3) + 8 * (reg >> 2);
                    float v = acc[mt][nt][reg] * linv[rl];
                    v = v > 0.f ? v : expm1f(v);   // elu (layer 1)
                    outbf[((size_t)b * Nn + i0 + rl) * ldo + (size_t)hd * Oo + o] = f2bf(v);
                }
            }
    } else {
        if (t < 64)
            plsum[((size_t)js * Bb + b) * Nn + i0 + t] =
                lred[t][0] + lred[t][1] + lred[t][2] + lred[t][3];
        float* pa = pacc + (((size_t)js * Bb + b) * Nn) * 256;
#pragma unroll
        for (int mt = 0; mt < 2; ++mt)
#pragma unroll
            for (int nt = 0; nt < 2; ++nt) {
                int o = wv * 64 + nt * 32 + lm;
#pragma unroll
                for (int reg = 0; reg < 16; ++reg) {
                    int rl = mt * 32 + 4 * kh + (reg & 3) + 8 * (reg >> 2);
                    pa[(size_t)(i0 + rl) * 256 + o] = acc[mt][nt][reg];
                }
            }
    }
}

// ---------------- combine 8 partials: x2 = Σacc/Σl + lin + b ----------------
__global__ __launch_bounds__(256) void combine8_kernel(
        const float* __restrict__ pacc, const float* __restrict__ plsum,
        const float* __restrict__ lin, const float* __restrict__ bias,
        unsigned short* __restrict__ out) {
    int gid = blockIdx.x * 256 + threadIdx.x;
    int row = gid >> 6;
    int o4 = gid & 63;
    size_t ps4 = (size_t)Bb * Nn * 64;
    const float4* p = (const float4*)pacc + (size_t)row * 64 + o4;
    float4 s = p[0];
#pragma unroll
    for (int k = 1; k < 8; ++k) {
        float4 q = p[k * ps4];
        s.x += q.x; s.y += q.y; s.z += q.z; s.w += q.w;
    }
    int BN = Bb * Nn;
    float lsum = 0.f;
#pragma unroll
    for (int k = 0; k < 8; ++k) lsum += plsum[row + k * BN];
    float li = 1.f / lsum;
    float4 lv = ((const float4*)lin)[(size_t)row * 64 + o4];
    float4 bv = ((const float4*)bias)[o4];
    float4 v;
    v.x = s.x * li + lv.x + bv.x; v.y = s.y * li + lv.y + bv.y;
    v.z = s.z * li + lv.z + bv.z; v.w = s.w * li + lv.w + bv.w;
    __hip_bfloat162 h0 = __float22bfloat162_rn(make_float2(v.x, v.y));
    __hip_bfloat162 h1 = __float22bfloat162_rn(make_float2(v.z, v.w));
    uint2 st; st.x = *(unsigned*)&h0; st.y = *(unsigned*)&h1;
    *(uint2*)(out + (size_t)gid * 4) = st;
}

extern "C" void kernel_launch(void* const* d_in, const int* in_sizes, int n_in,
                              void* d_out, int out_size, void* d_ws, size_t ws_size,
                              hipStream_t stream) {
    const float* x       = (const float*)d_in[0];
    const float* adj     = (const float*)d_in[1];
    const float* W_heads = (const float*)d_in[3];
    const float* a_heads = (const float*)d_in[4];
    const float* W_out   = (const float*)d_in[5];
    const float* a_out   = (const float*)d_in[6];
    const float* W_lin   = (const float*)d_in[7];
    const float* b_lin   = (const float*)d_in[8];
    const float* W_ln    = (const float*)d_in[9];
    const float* b_ln    = (const float*)d_in[10];

    char* w = (char*)d_ws;
    float* pacc     = (float*)(w);                    // 8x4 MB = 32 MiB (sh partials)
    float* lin      = (float*)(w + 33554432);
    float* E1p_mh   = (float*)(w + 41943040);         // also plsum after mh dead
    float* E1n_mh   = (float*)(w + 42074112);
    float2* E2pn_mh = (float2*)(w + 42205184);
    float* E1p_sh   = (float*)(w + 42467328);
    float* E1n_sh   = (float*)(w + 42483712);
    float2* E2pn_sh = (float2*)(w + 42500096);
    unsigned long long* bits = (unsigned long long*)(w + 42532864);   // 1 MB
    unsigned short* x_bf  = (unsigned short*)(w + 43581440);
    unsigned short* x2_bf = (unsigned short*)(w + 43581440);   // reuse after gemm1
    unsigned short* WhF   = (unsigned short*)(w + 49872896);
    unsigned short* WoF   = (unsigned short*)(w + 53018624);
    unsigned short* WlF   = (unsigned short*)(w + 54067200);
    unsigned short* WnF   = (unsigned short*)(w + 55115776);
    unsigned short* hfrag = (unsigned short*)(w + 55246848);   // 16 MB
    unsigned short* h2frag= (unsigned short*)(w + 72024064);   // 2 MB
    unsigned short* x1_bf = (unsigned short*)(w + 74121216);
    float* plsum = E1p_mh;

    // 0) prep
    adjbits_kernel<<<(Bb * Nn * Nn) / 256, 256, 0, stream>>>(adj, bits);
    cast_bf_kernel<<<(Bb * Nn * Ff) / 1024, 256, 0, stream>>>(x, x_bf);
    wfrag_kn_kernel<<<dim3(96, Hh), 256, 0, stream>>>(
        W_heads, WhF, Ff, Oo, (long long)Ff * Oo, 384LL * 512);
    wfrag_kn_kernel<<<dim3(256, 1), 256, 0, stream>>>(
        W_out, WoF, Hh * Oo, Oo, 0, 0);
    wfrag_nk_kernel<<<256, 256, 0, stream>>>(W_lin, WlF, Hh * Oo);
    wfrag_nk_kernel<<<32, 256, 0, stream>>>(W_ln, WnF, Oo);

    // 1) h = x @ W_heads -> hfrag + fused mh scores/exp
    gemm_bf_kernel<<<dim3(Nn / 64, 1, Bb * Hh), 256, 0, stream>>>(
        x_bf, Ff, (long long)Nn * Ff, 3, WhF, 384LL * 512, 7,
        nullptr, 0, hfrag, 524288, Nn, nullptr, 1,
        a_heads, 7, E1p_mh, E1n_mh, E2pn_mh);
    // 2) multihead attention + elu -> x1_bf  (bh-major grid: XCD = bh%8)
    attn_v5_kernel<2048, 0, 1><<<dim3(Bb * Hh, Nn / 64, 1), 256, 0, stream>>>(
        hfrag, (const unsigned*)bits, E1p_mh, E1n_mh, E2pn_mh,
        x1_bf, Hh * Oo, nullptr, nullptr, 3);
    // 3) fused dual GEMM: h2frag (+sh scores) and lin
    gemm_dual_kernel<<<dim3(Nn / 64, 2, Bb), 256, 0, stream>>>(
        x1_bf, Hh * Oo, (long long)Nn * Hh * Oo, WoF, h2frag, lin,
        a_out, E1p_sh, E1n_sh, E2pn_sh);
    // 4) single-head attention, 8-way j-split partials
    attn_v5_kernel<256, 1, 0><<<dim3(Nn / 64, Bb, 8), 256, 0, stream>>>(
        h2frag, (const unsigned*)bits, E1p_sh, E1n_sh, E2pn_sh,
        nullptr, 0, pacc, plsum, 0);
    // 5) combine -> x2_bf
    combine8_kernel<<<(Bb * Nn * 64) / 256, 256, 0, stream>>>(pacc, plsum, lin, b_lin, x2_bf);
    // 6) out = relu(x2 @ W_ln^T + b_ln)
    gemm_bf_kernel<<<dim3(Nn / 64, 1, Bb), 256, 0, stream>>>(
        x2_bf, Oo, (long long)Nn * Oo, 0, WnF, 0, 0,
        (float*)d_out, (long long)Nn * Oo, nullptr, 0, Nn, b_ln, 2,
        nullptr, 0, nullptr, nullptr, nullptr);
}

// Round 12
// 291.788 us; speedup vs baseline: 1.7735x; 1.0183x over previous
//
#include <hip/hip_runtime.h>
#include <hip/hip_bf16.h>

constexpr int Bb = 2, Nn = 2048, Ff = 768, Hh = 8, Oo = 256;

typedef __attribute__((ext_vector_type(8)))  short   short8;
typedef __attribute__((ext_vector_type(16))) float   f32x16;
typedef __attribute__((ext_vector_type(4)))  unsigned short ushort4_t;

__device__ inline unsigned short f2bf(float f) {
    unsigned u = __float_as_uint(f);
    u = (u + 0x7FFFu + ((u >> 16) & 1u)) >> 16;   // RNE
    return (unsigned short)u;
}

// ---------------- adjacency bitmask ----------------
__global__ __launch_bounds__(256) void adjbits_kernel(
        const float* __restrict__ adj, unsigned long long* __restrict__ bits) {
    size_t gid = (size_t)blockIdx.x * 256 + threadIdx.x;
    float v = adj[gid];
    unsigned long long m = __ballot(v > 0.f);
    if ((threadIdx.x & 63) == 0) bits[gid >> 6] = m;
}

// ---------------- f32 -> bf16 flat cast ----------------
__global__ __launch_bounds__(256) void cast_bf_kernel(
        const float* __restrict__ in, unsigned short* __restrict__ out) {
    size_t i = (size_t)blockIdx.x * 256 + threadIdx.x;
    float4 v = ((const float4*)in)[i];
    ushort4_t o;
    o.x = f2bf(v.x); o.y = f2bf(v.y); o.z = f2bf(v.z); o.w = f2bf(v.w);
    ((ushort4_t*)out)[i] = o;
}

// ======== B-fragment layout: frag id = nt32*(K/16)+kt, 1 KB each ========
__global__ __launch_bounds__(256) void wfrag_kn_kernel(
        const float* __restrict__ W, unsigned short* __restrict__ out,
        int K, int N, long long sW, long long sO) {
    W   += (size_t)blockIdx.y * sW;
    out += (size_t)blockIdx.y * sO;
    int t = threadIdx.x;
    int f = blockIdx.x * 4 + (t >> 6);
    int slot = t & 63, kh = slot >> 5, lm = slot & 31;
    int nfk = K >> 4;
    int nt = f / nfk, kt = f - nt * nfk;
    const float* wp = W + (size_t)(kt * 16 + kh * 8) * N + nt * 32 + lm;
    ushort4_t o0, o1;
    o0.x = f2bf(wp[0]);             o0.y = f2bf(wp[(size_t)N]);
    o0.z = f2bf(wp[2 * (size_t)N]); o0.w = f2bf(wp[3 * (size_t)N]);
    o1.x = f2bf(wp[4 * (size_t)N]); o1.y = f2bf(wp[5 * (size_t)N]);
    o1.z = f2bf(wp[6 * (size_t)N]); o1.w = f2bf(wp[7 * (size_t)N]);
    unsigned short* op = out + (size_t)f * 512 + slot * 8;
    *(ushort4_t*)op = o0;
    *(ushort4_t*)(op + 4) = o1;
}

__global__ __launch_bounds__(256) void wfrag_nk_kernel(
        const float* __restrict__ W, unsigned short* __restrict__ out, int K) {
    int t = threadIdx.x;
    int f = blockIdx.x * 4 + (t >> 6);
    int slot = t & 63, kh = slot >> 5, lm = slot & 31;
    int nfk = K >> 4;
    int nt = f / nfk, kt = f - nt * nfk;
    const float* wp = W + (size_t)(nt * 32 + lm) * K + kt * 16 + kh * 8;
    float4 a = *(const float4*)wp, b = *(const float4*)(wp + 4);
    ushort4_t o0, o1;
    o0.x = f2bf(a.x); o0.y = f2bf(a.y); o0.z = f2bf(a.z); o0.w = f2bf(a.w);
    o1.x = f2bf(b.x); o1.y = f2bf(b.y); o1.z = f2bf(b.z); o1.w = f2bf(b.w);
    unsigned short* op = out + (size_t)f * 512 + slot * 8;
    *(ushort4_t*)op = o0;
    *(ushort4_t*)(op + 4) = o1;
}

// ---------------- MFMA GEMM, BK=64, optional fused scores epilogue ----------------
__global__ __launch_bounds__(256) void gemm_bf_kernel(
        const unsigned short* __restrict__ A, int K, long long sA, int bAshift,
        const unsigned short* __restrict__ BF, long long sB, int bmask,
        float* __restrict__ C, long long sC,
        unsigned short* __restrict__ CF, long long sCF, int Mtot,
        const float* __restrict__ bias, int mode,
        const float* __restrict__ aall, int amask,
        float* __restrict__ E1p, float* __restrict__ E1n, float2* __restrict__ E2pn) {
    int z = blockIdx.z;
    A  += (size_t)(z >> bAshift) * sA;
    BF += (size_t)(z & bmask) * sB;
    if (C) C += (size_t)z * sC;
    if (CF) CF += (size_t)z * sCF;
    int m0 = blockIdx.x * 64;
    int t = threadIdx.x;
    int wv = t >> 6, lane = t & 63;
    int lm = lane & 31, kh = lane >> 5;
    int nfk = K >> 4;
    __shared__ __align__(16) unsigned short As[64][72];
    f32x16 acc[2][2] = {};
    int sr = t >> 2, sc2 = (t & 3) * 16;
    const unsigned short* ag  = A + (size_t)(m0 + sr) * K + sc2;
    const unsigned short* bg0 = BF + (size_t)(wv * 2) * nfk * 512;
    const unsigned short* bg1 = bg0 + (size_t)nfk * 512;
    for (int k0 = 0; k0 < K; k0 += 64) {
        *(short8*)&As[sr][sc2]     = *(const short8*)(ag + k0);
        *(short8*)&As[sr][sc2 + 8] = *(const short8*)(ag + k0 + 8);
        int kt0 = k0 >> 4;
        __syncthreads();
#pragma unroll
        for (int s = 0; s < 4; ++s) {
            short8 a0 = *(const short8*)&As[lm][s * 16 + kh * 8];
            short8 a1 = *(const short8*)&As[32 + lm][s * 16 + kh * 8];
            short8 b0 = *(const short8*)(bg0 + (size_t)(kt0 + s) * 512 + lane * 8);
            short8 b1 = *(const short8*)(bg1 + (size_t)(kt0 + s) * 512 + lane * 8);
            acc[0][0] = __builtin_amdgcn_mfma_f32_32x32x16_bf16(a0, b0, acc[0][0], 0, 0, 0);
            acc[0][1] = __builtin_amdgcn_mfma_f32_32x32x16_bf16(a0, b1, acc[0][1], 0, 0, 0);
            acc[1][0] = __builtin_amdgcn_mfma_f32_32x32x16_bf16(a1, b0, acc[1][0], 0, 0, 0);
            acc[1][1] = __builtin_amdgcn_mfma_f32_32x32x16_bf16(a1, b1, acc[1][1], 0, 0, 0);
        }
        __syncthreads();
    }
#pragma unroll
    for (int mt = 0; mt < 2; ++mt)
#pragma unroll
        for (int nt = 0; nt < 2; ++nt) {
            int colg = wv * 64 + nt * 32 + lm;
            float bv = (mode == 2) ? bias[colg] : 0.f;
            if (C) {
#pragma unroll
                for (int reg = 0; reg < 16; ++reg) {
                    int rl = mt * 32 + 4 * kh + (reg & 3) + 8 * (reg >> 2);
                    float v = acc[mt][nt][reg];
                    if (mode == 2) { v += bv; v = fmaxf(v, 0.f); }
                    C[(size_t)(m0 + rl) * 256 + colg] = v;
                }
            }
            if (mode == 1) {
#pragma unroll
                for (int q = 0; q < 4; ++q) {
                    int kt = m0 / 16 + mt * 2 + (q >> 1);
                    size_t fi = ((size_t)(colg >> 5) * (Mtot / 16) + kt) * 512 +
                                ((q & 1) * 32 + (colg & 31)) * 8 + kh * 4;
                    ushort4_t pk;
                    pk.x = f2bf(acc[mt][nt][q * 4 + 0]);
                    pk.y = f2bf(acc[mt][nt][q * 4 + 1]);
                    pk.z = f2bf(acc[mt][nt][q * 4 + 2]);
                    pk.w = f2bf(acc[mt][nt][q * 4 + 3]);
                    *(ushort4_t*)(CF + fi) = pk;
                }
            }
        }
    if (aall) {
        const float* av = aall + (size_t)(z & amask) * 512;
        float a1v0 = av[wv * 64 + lm],       a1v1 = av[wv * 64 + 32 + lm];
        float a2v0 = av[256 + wv * 64 + lm], a2v1 = av[256 + wv * 64 + 32 + lm];
        float* sbuf = (float*)As;
#pragma unroll
        for (int mt = 0; mt < 2; ++mt)
#pragma unroll
            for (int reg = 0; reg < 16; ++reg) {
                int rl = mt * 32 + 4 * kh + (reg & 3) + 8 * (reg >> 2);
                float v1 = acc[mt][0][reg] * a1v0 + acc[mt][1][reg] * a1v1;
                float v2 = acc[mt][0][reg] * a2v0 + acc[mt][1][reg] * a2v1;
#pragma unroll
                for (int m = 1; m <= 16; m <<= 1) {
                    v1 += __shfl_xor(v1, m, 64);
                    v2 += __shfl_xor(v2, m, 64);
                }
                if (lm == 0) { sbuf[rl * 8 + wv] = v1; sbuf[rl * 8 + 4 + wv] = v2; }
            }
        __syncthreads();
        if (t < 64) {
            float s1 = sbuf[t * 8] + sbuf[t * 8 + 1] + sbuf[t * 8 + 2] + sbuf[t * 8 + 3];
            float s2 = sbuf[t * 8 + 4] + sbuf[t * 8 + 5] + sbuf[t * 8 + 6] + sbuf[t * 8 + 7];
            size_t ei = (size_t)z * Nn + m0 + t;
            E1p[ei] = __expf(s1);
            E1n[ei] = __expf(0.2f * s1);
            E2pn[ei] = make_float2(__expf(s2), __expf(0.2f * s2));
        }
    }
}

// ---------------- dual MFMA GEMM, BK=64: x1 @ [WoF ; WlF]; ng0 + fused sh scores ----------------
__global__ __launch_bounds__(256) void gemm_dual_kernel(
        const unsigned short* __restrict__ A, int K, long long sA,
        const unsigned short* __restrict__ BF,
        unsigned short* __restrict__ h2f, float* __restrict__ lin,
        const float* __restrict__ a_out,
        float* __restrict__ E1p, float* __restrict__ E1n, float2* __restrict__ E2pn) {
    int b = blockIdx.z, ng = blockIdx.y;
    A += (size_t)b * sA;
    int nfk = K >> 4;
    BF += (size_t)ng * 8 * nfk * 512;
    int m0 = blockIdx.x * 64;
    int t = threadIdx.x;
    int wv = t >> 6, lane = t & 63;
    int lm = lane & 31, kh = lane >> 5;
    __shared__ __align__(16) unsigned short As[64][72];
    f32x16 acc[2][2] = {};
    int sr = t >> 2, sc2 = (t & 3) * 16;
    const unsigned short* ag  = A + (size_t)(m0 + sr) * K + sc2;
    const unsigned short* bg0 = BF + (size_t)(wv * 2) * nfk * 512;
    const unsigned short* bg1 = bg0 + (size_t)nfk * 512;
    for (int k0 = 0; k0 < K; k0 += 64) {
        *(short8*)&As[sr][sc2]     = *(const short8*)(ag + k0);
        *(short8*)&As[sr][sc2 + 8] = *(const short8*)(ag + k0 + 8);
        int kt0 = k0 >> 4;
        __syncthreads();
#pragma unroll
        for (int s = 0; s < 4; ++s) {
            short8 a0 = *(const short8*)&As[lm][s * 16 + kh * 8];
            short8 a1 = *(const short8*)&As[32 + lm][s * 16 + kh * 8];
            short8 b0 = *(const short8*)(bg0 + (size_t)(kt0 + s) * 512 + lane * 8);
            short8 b1 = *(const short8*)(bg1 + (size_t)(kt0 + s) * 512 + lane * 8);
            acc[0][0] = __builtin_amdgcn_mfma_f32_32x32x16_bf16(a0, b0, acc[0][0], 0, 0, 0);
            acc[0][1] = __builtin_amdgcn_mfma_f32_32x32x16_bf16(a0, b1, acc[0][1], 0, 0, 0);
            acc[1][0] = __builtin_amdgcn_mfma_f32_32x32x16_bf16(a1, b0, acc[1][0], 0, 0, 0);
            acc[1][1] = __builtin_amdgcn_mfma_f32_32x32x16_bf16(a1, b1, acc[1][1], 0, 0, 0);
        }
        __syncthreads();
    }
    if (ng == 1) {
        float* C = lin + (size_t)b * Nn * 256;
#pragma unroll
        for (int mt = 0; mt < 2; ++mt)
#pragma unroll
            for (int nt = 0; nt < 2; ++nt) {
                int colg = wv * 64 + nt * 32 + lm;
#pragma unroll
                for (int reg = 0; reg < 16; ++reg) {
                    int rl = mt * 32 + 4 * kh + (reg & 3) + 8 * (reg >> 2);
                    C[(size_t)(m0 + rl) * 256 + colg] = acc[mt][nt][reg];
                }
            }
    } else {
        unsigned short* CF = h2f + (size_t)b * 524288;
#pragma unroll
        for (int mt = 0; mt < 2; ++mt)
#pragma unroll
            for (int nt = 0; nt < 2; ++nt) {
                int colg = wv * 64 + nt * 32 + lm;
#pragma unroll
                for (int q = 0; q < 4; ++q) {
                    int kt = m0 / 16 + mt * 2 + (q >> 1);
                    size_t fi = ((size_t)(colg >> 5) * 128 + kt) * 512 +
                                ((q & 1) * 32 + (colg & 31)) * 8 + kh * 4;
                    ushort4_t pk;
                    pk.x = f2bf(acc[mt][nt][q * 4 + 0]);
                    pk.y = f2bf(acc[mt][nt][q * 4 + 1]);
                    pk.z = f2bf(acc[mt][nt][q * 4 + 2]);
                    pk.w = f2bf(acc[mt][nt][q * 4 + 3]);
                    *(ushort4_t*)(CF + fi) = pk;
                }
            }
        float a1v0 = a_out[wv * 64 + lm],       a1v1 = a_out[wv * 64 + 32 + lm];
        float a2v0 = a_out[256 + wv * 64 + lm], a2v1 = a_out[256 + wv * 64 + 32 + lm];
        float* sbuf = (float*)As;
#pragma unroll
        for (int mt = 0; mt < 2; ++mt)
#pragma unroll
            for (int reg = 0; reg < 16; ++reg) {
                int rl = mt * 32 + 4 * kh + (reg & 3) + 8 * (reg >> 2);
                float v1 = acc[mt][0][reg] * a1v0 + acc[mt][1][reg] * a1v1;
                float v2 = acc[mt][0][reg] * a2v0 + acc[mt][1][reg] * a2v1;
#pragma unroll
                for (int m = 1; m <= 16; m <<= 1) {
                    v1 += __shfl_xor(v1, m, 64);
                    v2 += __shfl_xor(v2, m, 64);
                }
                if (lm == 0) { sbuf[rl * 8 + wv] = v1; sbuf[rl * 8 + 4 + wv] = v2; }
            }
        __syncthreads();
        if (t < 64) {
            float s1 = sbuf[t * 8] + sbuf[t * 8 + 1] + sbuf[t * 8 + 2] + sbuf[t * 8 + 3];
            float s2 = sbuf[t * 8 + 4] + sbuf[t * 8 + 5] + sbuf[t * 8 + 6] + sbuf[t * 8 + 7];
            size_t ei = (size_t)b * Nn + m0 + t;
            E1p[ei] = __expf(s1);
            E1n[ei] = __expf(0.2f * s1);
            E2pn[ei] = make_float2(__expf(s2), __expf(0.2f * s2));
        }
    }
}

// ---------------- attention v6: 128-j phases (1 barrier each), frag B, lp[4] ----------------
template<int JLEN, int MODE, int SWAPXY>
__global__ __launch_bounds__(256, 2) void attn_v6_kernel(
        const unsigned short* __restrict__ hfrag,
        const unsigned* __restrict__ bits,
        const float* __restrict__ E1p, const float* __restrict__ E1n,
        const float2* __restrict__ E2pn,
        unsigned short* __restrict__ outbf, int ldo,
        float* __restrict__ pacc, float* __restrict__ plsum,
        int hshift) {
    constexpr int W = JLEN / 32, NC = JLEN / 64, ABS = W + 1;
    int it = SWAPXY ? blockIdx.y : blockIdx.x;
    int bh = SWAPXY ? blockIdx.x : blockIdx.y;
    int js = blockIdx.z;
    int b = bh >> hshift, hd = bh & ((1 << hshift) - 1);
    int i0 = it * 64, jbase = js * JLEN;
    int kt0 = js * (JLEN / 16);
    int t = threadIdx.x, lane = t & 63;
    int wv = t >> 6, lm = lane & 31, kh = lane >> 5;
    int ti = lane, jq = wv;

    __shared__ unsigned ab[64 * ABS];
    __shared__ __align__(16) unsigned short ps[2][64][128];   // 128-j phases
    __shared__ float lred[64][5];
    __shared__ float linv[64];

    const unsigned* bb = bits + ((size_t)b * Nn + i0) * 64 + (jbase >> 5);
    for (int k = t; k < 64 * W; k += 256) {
        int r = k / W, w0 = k - r * W;
        ab[r * ABS + w0] = bb[(size_t)r * 64 + w0];
    }
    __syncthreads();   // ab[] visible before computePhase

    float e1p = E1p[(size_t)bh * Nn + i0 + ti];
    float e1n = E1n[(size_t)bh * Nn + i0 + ti];
    const float4* e2base = (const float4*)(E2pn + (size_t)bh * Nn + jbase);

    const unsigned short* bg0 = hfrag + (size_t)bh * 524288 + (size_t)(wv * 2) * 128 * 512;
    const unsigned short* bg1 = bg0 + 128 * 512;

    f32x16 acc[2][2] = {};
    float lp[4] = {0.f, 0.f, 0.f, 0.f};   // independent chains
    short8 B0[8], B1[8];

    auto loadB = [&](int c, short8* B) {
#pragma unroll
        for (int s = 0; s < 4; ++s) {
            int kt = kt0 + c * 4 + s;
            B[2 * s]     = *(const short8*)(bg0 + (size_t)kt * 512 + lane * 8);
            B[2 * s + 1] = *(const short8*)(bg1 + (size_t)kt * 512 + lane * 8);
        }
    };
    // one phase = 128 j; thread (ti,jq) covers j = ph*128 + jq*32 .. +31 (one u32 of bits)
    auto computePhase = [&](int ph, int buf) {
        int cj = ph * 128;
        unsigned word = ab[ti * ABS + (cj >> 5) + jq];
        const float4* ep = e2base + ((cj + jq * 32) >> 1);
        unsigned sw = ti & 15;
#pragma unroll
        for (int v = 0; v < 4; ++v) {
            unsigned pk[4];
#pragma unroll
            for (int u = 0; u < 4; ++u) {
                float4 q = ep[v * 4 + u];
                float p0 = fmaxf(e1p * q.x, e1n * q.y);   // select==max (exact)
                p0 = ((word >> (v * 8 + u * 2)) & 1u) ? p0 : 0.f;
                float p1 = fmaxf(e1p * q.z, e1n * q.w);
                p1 = ((word >> (v * 8 + u * 2 + 1)) & 1u) ? p1 : 0.f;
                lp[u] += p0 + p1;
                __hip_bfloat162 hv = __float22bfloat162_rn(make_float2(p0, p1));
                pk[u] = *(unsigned*)&hv;
            }
            uint4 v4; v4.x = pk[0]; v4.y = pk[1]; v4.z = pk[2]; v4.w = pk[3];
            *(uint4*)&ps[buf][ti][(((jq << 2) | v) ^ sw) * 8] = v4;
        }
    };
    auto mfmaStep = [&](int buf, int sub, short8* B) {
        unsigned sw = lm & 15;
#pragma unroll
        for (int s = 0; s < 4; ++s) {
            int g = sub * 8 + 2 * s + kh;
            short8 a0 = *(const short8*)&ps[buf][lm][(g ^ sw) * 8];
            short8 a1 = *(const short8*)&ps[buf][32 + lm][(g ^ sw) * 8];
            acc[0][0] = __builtin_amdgcn_mfma_f32_32x32x16_bf16(a0, B[2 * s],     acc[0][0], 0, 0, 0);
            acc[0][1] = __builtin_amdgcn_mfma_f32_32x32x16_bf16(a0, B[2 * s + 1], acc[0][1], 0, 0, 0);
            acc[1][0] = __builtin_amdgcn_mfma_f32_32x32x16_bf16(a1, B[2 * s],     acc[1][0], 0, 0, 0);
            acc[1][1] = __builtin_amdgcn_mfma_f32_32x32x16_bf16(a1, B[2 * s + 1], acc[1][1], 0, 0, 0);
        }
    };

    computePhase(0, 0);
    loadB(0, B0);
    __syncthreads();
    for (int c = 0; c < NC; c += 2) {
        int pb = (c >> 1) & 1;
        loadB(c + 1, B1);
        mfmaStep(pb, 0, B0);
        if (c + 2 < NC) {
            computePhase(c / 2 + 1, pb ^ 1);   // buffer last read before previous barrier
            loadB(c + 2, B0);
        }
        mfmaStep(pb, 1, B1);
        __syncthreads();
    }

    lred[ti][jq] = lp[0] + lp[1] + lp[2] + lp[3];
    __syncthreads();
    if (MODE == 0) {
        if (t < 64) linv[t] = 1.f / (lred[t][0] + lred[t][1] + lred[t][2] + lred[t][3]);
        __syncthreads();
#pragma unroll
        for (int mt = 0; mt < 2; ++mt)
#pragma unroll
            for (int nt = 0; nt < 2; ++nt) {
                int o = wv * 64 + nt * 32 + lm;
#pragma unroll
                for (int reg = 0; reg < 16; ++reg) {
                    int rl = mt * 32 + 4 * kh + (reg & 3) + 8 * (reg >> 2);
                    float v = acc[mt][nt][reg] * linv[rl];
                    v = v > 0.f ? v : expm1f(v);   // elu (layer 1)
                    outbf[((size_t)b * Nn + i0 + rl) * ldo + (size_t)hd * Oo + o] = f2bf(v);
                }
            }
    } else {
        if (t < 64)
            plsum[((size_t)js * Bb + b) * Nn + i0 + t] =
                lred[t][0] + lred[t][1] + lred[t][2] + lred[t][3];
        float* pa = pacc + (((size_t)js * Bb + b) * Nn) * 256;
#pragma unroll
        for (int mt = 0; mt < 2; ++mt)
#pragma unroll
            for (int nt = 0; nt < 2; ++nt) {
                int o = wv * 64 + nt * 32 + lm;
#pragma unroll
                for (int reg = 0; reg < 16; ++reg) {
                    int rl = mt * 32 + 4 * kh + (reg & 3) + 8 * (reg >> 2);
                    pa[(size_t)(i0 + rl) * 256 + o] = acc[mt][nt][reg];
                }
            }
    }
}

// ---------------- combine 8 partials: x2 = Σacc/Σl + lin + b ----------------
__global__ __launch_bounds__(256) void combine8_kernel(
        const float* __restrict__ pacc, const float* __restrict__ plsum,
        const float* __restrict__ lin, const float* __restrict__ bias,
        unsigned short* __restrict__ out) {
    int gid = blockIdx.x * 256 + threadIdx.x;
    int row = gid >> 6;
    int o4 = gid & 63;
    size_t ps4 = (size_t)Bb * Nn * 64;
    const float4* p = (const float4*)pacc + (size_t)row * 64 + o4;
    float4 s = p[0];
#pragma unroll
    for (int k = 1; k < 8; ++k) {
        float4 q = p[k * ps4];
        s.x += q.x; s.y += q.y; s.z += q.z; s.w += q.w;
    }
    int BN = Bb * Nn;
    float lsum = 0.f;
#pragma unroll
    for (int k = 0; k < 8; ++k) lsum += plsum[row + k * BN];
    float li = 1.f / lsum;
    float4 lv = ((const float4*)lin)[(size_t)row * 64 + o4];
    float4 bv = ((const float4*)bias)[o4];
    float4 v;
    v.x = s.x * li + lv.x + bv.x; v.y = s.y * li + lv.y + bv.y;
    v.z = s.z * li + lv.z + bv.z; v.w = s.w * li + lv.w + bv.w;
    __hip_bfloat162 h0 = __float22bfloat162_rn(make_float2(v.x, v.y));
    __hip_bfloat162 h1 = __float22bfloat162_rn(make_float2(v.z, v.w));
    uint2 st; st.x = *(unsigned*)&h0; st.y = *(unsigned*)&h1;
    *(uint2*)(out + (size_t)gid * 4) = st;
}

extern "C" void kernel_launch(void* const* d_in, const int* in_sizes, int n_in,
                              void* d_out, int out_size, void* d_ws, size_t ws_size,
                              hipStream_t stream) {
    const float* x       = (const float*)d_in[0];
    const float* adj     = (const float*)d_in[1];
    const float* W_heads = (const float*)d_in[3];
    const float* a_heads = (const float*)d_in[4];
    const float* W_out   = (const float*)d_in[5];
    const float* a_out   = (const float*)d_in[6];
    const float* W_lin   = (const float*)d_in[7];
    const float* b_lin   = (const float*)d_in[8];
    const float* W_ln    = (const float*)d_in[9];
    const float* b_ln    = (const float*)d_in[10];

    char* w = (char*)d_ws;
    float* pacc     = (float*)(w);                    // 8x4 MB (sh partials)
    float* lin      = (float*)(w + 33554432);
    float* E1p_mh   = (float*)(w + 41943040);
    float* E1n_mh   = (float*)(w + 42074112);
    float2* E2pn_mh = (float2*)(w + 42205184);
    float* E1p_sh   = (float*)(w + 42467328);
    float* E1n_sh   = (float*)(w + 42483712);
    float2* E2pn_sh = (float2*)(w + 42500096);
    unsigned long long* bits = (unsigned long long*)(w + 42532864);
    unsigned short* x_bf  = (unsigned short*)(w + 43581440);
    unsigned short* x2_bf = (unsigned short*)(w + 43581440);   // reuse after gemm1
    unsigned short* WhF   = (unsigned short*)(w + 49872896);
    unsigned short* WoF   = (unsigned short*)(w + 53018624);
    unsigned short* WlF   = (unsigned short*)(w + 54067200);
    unsigned short* WnF   = (unsigned short*)(w + 55115776);
    unsigned short* hfrag = (unsigned short*)(w + 55246848);   // 16 MB
    unsigned short* h2frag= (unsigned short*)(w + 72024064);   // 2 MB
    unsigned short* x1_bf = (unsigned short*)(w + 74121216);
    float* plsum = E1p_mh;

    // 0) prep
    adjbits_kernel<<<(Bb * Nn * Nn) / 256, 256, 0, stream>>>(adj, bits);
    cast_bf_kernel<<<(Bb * Nn * Ff) / 1024, 256, 0, stream>>>(x, x_bf);
    wfrag_kn_kernel<<<dim3(96, Hh), 256, 0, stream>>>(
        W_heads, WhF, Ff, Oo, (long long)Ff * Oo, 384LL * 512);
    wfrag_kn_kernel<<<dim3(256, 1), 256, 0, stream>>>(
        W_out, WoF, Hh * Oo, Oo, 0, 0);
    wfrag_nk_kernel<<<256, 256, 0, stream>>>(W_lin, WlF, Hh * Oo);
    wfrag_nk_kernel<<<32, 256, 0, stream>>>(W_ln, WnF, Oo);

    // 1) h = x @ W_heads -> hfrag + fused mh scores/exp
    gemm_bf_kernel<<<dim3(Nn / 64, 1, Bb * Hh), 256, 0, stream>>>(
        x_bf, Ff, (long long)Nn * Ff, 3, WhF, 384LL * 512, 7,
        nullptr, 0, hfrag, 524288, Nn, nullptr, 1,
        a_heads, 7, E1p_mh, E1n_mh, E2pn_mh);
    // 2) multihead attention + elu -> x1_bf  (bh-major grid: XCD = bh%8)
    attn_v6_kernel<2048, 0, 1><<<dim3(Bb * Hh, Nn / 64, 1), 256, 0, stream>>>(
        hfrag, (const unsigned*)bits, E1p_mh, E1n_mh, E2pn_mh,
        x1_bf, Hh * Oo, nullptr, nullptr, 3);
    // 3) fused dual GEMM: h2frag (+sh scores) and lin
    gemm_dual_kernel<<<dim3(Nn / 64, 2, Bb), 256, 0, stream>>>(
        x1_bf, Hh * Oo, (long long)Nn * Hh * Oo, WoF, h2frag, lin,
        a_out, E1p_sh, E1n_sh, E2pn_sh);
    // 4) single-head attention, 8-way j-split partials
    attn_v6_kernel<256, 1, 0><<<dim3(Nn / 64, Bb, 8), 256, 0, stream>>>(
        h2frag, (const unsigned*)bits, E1p_sh, E1n_sh, E2pn_sh,
        nullptr, 0, pacc, plsum, 0);
    // 5) combine -> x2_bf
    combine8_kernel<<<(Bb * Nn * 64) / 256, 256, 0, stream>>>(pacc, plsum, lin, b_lin, x2_bf);
    // 6) out = relu(x2 @ W_ln^T + b_ln)
    gemm_bf_kernel<<<dim3(Nn / 64, 1, Bb), 256, 0, stream>>>(
        x2_bf, Oo, (long long)Nn * Oo, 0, WnF, 0, 0,
        (float*)d_out, (long long)Nn * Oo, nullptr, 0, Nn, b_ln, 2,
        nullptr, 0, nullptr, nullptr, nullptr);
}

// Round 13
// 283.865 us; speedup vs baseline: 1.8230x; 1.0279x over previous
//
#include <hip/hip_runtime.h>
#include <hip/hip_bf16.h>

constexpr int Bb = 2, Nn = 2048, Ff = 768, Hh = 8, Oo = 256;

typedef __attribute__((ext_vector_type(8)))  short   short8;
typedef __attribute__((ext_vector_type(16))) float   f32x16;
typedef __attribute__((ext_vector_type(4)))  unsigned short ushort4_t;

__device__ inline unsigned short f2bf(float f) {
    unsigned u = __float_as_uint(f);
    u = (u + 0x7FFFu + ((u >> 16) & 1u)) >> 16;   // RNE
    return (unsigned short)u;
}

// ---------------- adjacency bitmask ----------------
__global__ __launch_bounds__(256) void adjbits_kernel(
        const float* __restrict__ adj, unsigned long long* __restrict__ bits) {
    size_t gid = (size_t)blockIdx.x * 256 + threadIdx.x;
    float v = adj[gid];
    unsigned long long m = __ballot(v > 0.f);
    if ((threadIdx.x & 63) == 0) bits[gid >> 6] = m;
}

// ---------------- f32 -> bf16 flat cast ----------------
__global__ __launch_bounds__(256) void cast_bf_kernel(
        const float* __restrict__ in, unsigned short* __restrict__ out) {
    size_t i = (size_t)blockIdx.x * 256 + threadIdx.x;
    float4 v = ((const float4*)in)[i];
    ushort4_t o;
    o.x = f2bf(v.x); o.y = f2bf(v.y); o.z = f2bf(v.z); o.w = f2bf(v.w);
    ((ushort4_t*)out)[i] = o;
}

// ======== B-fragment layout: frag id = nt32*(K/16)+kt, 1 KB each ========
__global__ __launch_bounds__(256) void wfrag_kn_kernel(
        const float* __restrict__ W, unsigned short* __restrict__ out,
        int K, int N, long long sW, long long sO) {
    W   += (size_t)blockIdx.y * sW;
    out += (size_t)blockIdx.y * sO;
    int t = threadIdx.x;
    int f = blockIdx.x * 4 + (t >> 6);
    int slot = t & 63, kh = slot >> 5, lm = slot & 31;
    int nfk = K >> 4;
    int nt = f / nfk, kt = f - nt * nfk;
    const float* wp = W + (size_t)(kt * 16 + kh * 8) * N + nt * 32 + lm;
    ushort4_t o0, o1;
    o0.x = f2bf(wp[0]);             o0.y = f2bf(wp[(size_t)N]);
    o0.z = f2bf(wp[2 * (size_t)N]); o0.w = f2bf(wp[3 * (size_t)N]);
    o1.x = f2bf(wp[4 * (size_t)N]); o1.y = f2bf(wp[5 * (size_t)N]);
    o1.z = f2bf(wp[6 * (size_t)N]); o1.w = f2bf(wp[7 * (size_t)N]);
    unsigned short* op = out + (size_t)f * 512 + slot * 8;
    *(ushort4_t*)op = o0;
    *(ushort4_t*)(op + 4) = o1;
}

__global__ __launch_bounds__(256) void wfrag_nk_kernel(
        const float* __restrict__ W, unsigned short* __restrict__ out, int K) {
    int t = threadIdx.x;
    int f = blockIdx.x * 4 + (t >> 6);
    int slot = t & 63, kh = slot >> 5, lm = slot & 31;
    int nfk = K >> 4;
    int nt = f / nfk, kt = f - nt * nfk;
    const float* wp = W + (size_t)(nt * 32 + lm) * K + kt * 16 + kh * 8;
    float4 a = *(const float4*)wp, b = *(const float4*)(wp + 4);
    ushort4_t o0, o1;
    o0.x = f2bf(a.x); o0.y = f2bf(a.y); o0.z = f2bf(a.z); o0.w = f2bf(a.w);
    o1.x = f2bf(b.x); o1.y = f2bf(b.y); o1.z = f2bf(b.z); o1.w = f2bf(b.w);
    unsigned short* op = out + (size_t)f * 512 + slot * 8;
    *(ushort4_t*)op = o0;
    *(ushort4_t*)(op + 4) = o1;
}

// ---------------- MFMA GEMM, BK=64, optional fused scores epilogue ----------------
__global__ __launch_bounds__(256) void gemm_bf_kernel(
        const unsigned short* __restrict__ A, int K, long long sA, int bAshift,
        const unsigned short* __restrict__ BF, long long sB, int bmask,
        float* __restrict__ C, long long sC,
        unsigned short* __restrict__ CF, long long sCF, int Mtot,
        const float* __restrict__ bias, int mode,
        const float* __restrict__ aall, int amask,
        float* __restrict__ E1p, float* __restrict__ E1n, float2* __restrict__ E2pn) {
    int z = blockIdx.z;
    A  += (size_t)(z >> bAshift) * sA;
    BF += (size_t)(z & bmask) * sB;
    if (C) C += (size_t)z * sC;
    if (CF) CF += (size_t)z * sCF;
    int m0 = blockIdx.x * 64;
    int t = threadIdx.x;
    int wv = t >> 6, lane = t & 63;
    int lm = lane & 31, kh = lane >> 5;
    int nfk = K >> 4;
    __shared__ __align__(16) unsigned short As[64][72];
    f32x16 acc[2][2] = {};
    int sr = t >> 2, sc2 = (t & 3) * 16;
    const unsigned short* ag  = A + (size_t)(m0 + sr) * K + sc2;
    const unsigned short* bg0 = BF + (size_t)(wv * 2) * nfk * 512;
    const unsigned short* bg1 = bg0 + (size_t)nfk * 512;
    for (int k0 = 0; k0 < K; k0 += 64) {
        *(short8*)&As[sr][sc2]     = *(const short8*)(ag + k0);
        *(short8*)&As[sr][sc2 + 8] = *(const short8*)(ag + k0 + 8);
        int kt0 = k0 >> 4;
        __syncthreads();
#pragma unroll
        for (int s = 0; s < 4; ++s) {
            short8 a0 = *(const short8*)&As[lm][s * 16 + kh * 8];
            short8 a1 = *(const short8*)&As[32 + lm][s * 16 + kh * 8];
            short8 b0 = *(const short8*)(bg0 + (size_t)(kt0 + s) * 512 + lane * 8);
            short8 b1 = *(const short8*)(bg1 + (size_t)(kt0 + s) * 512 + lane * 8);
            acc[0][0] = __builtin_amdgcn_mfma_f32_32x32x16_bf16(a0, b0, acc[0][0], 0, 0, 0);
            acc[0][1] = __builtin_amdgcn_mfma_f32_32x32x16_bf16(a0, b1, acc[0][1], 0, 0, 0);
            acc[1][0] = __builtin_amdgcn_mfma_f32_32x32x16_bf16(a1, b0, acc[1][0], 0, 0, 0);
            acc[1][1] = __builtin_amdgcn_mfma_f32_32x32x16_bf16(a1, b1, acc[1][1], 0, 0, 0);
        }
        __syncthreads();
    }
#pragma unroll
    for (int mt = 0; mt < 2; ++mt)
#pragma unroll
        for (int nt = 0; nt < 2; ++nt) {
            int colg = wv * 64 + nt * 32 + lm;
            float bv = (mode == 2) ? bias[colg] : 0.f;
            if (C) {
#pragma unroll
                for (int reg = 0; reg < 16; ++reg) {
                    int rl = mt * 32 + 4 * kh + (reg & 3) + 8 * (reg >> 2);
                    float v = acc[mt][nt][reg];
                    if (mode == 2) { v += bv; v = fmaxf(v, 0.f); }
                    C[(size_t)(m0 + rl) * 256 + colg] = v;
                }
            }
            if (mode == 1) {
#pragma unroll
                for (int q = 0; q < 4; ++q) {
                    int kt = m0 / 16 + mt * 2 + (q >> 1);
                    size_t fi = ((size_t)(colg >> 5) * (Mtot / 16) + kt) * 512 +
                                ((q & 1) * 32 + (colg & 31)) * 8 + kh * 4;
                    ushort4_t pk;
                    pk.x = f2bf(acc[mt][nt][q * 4 + 0]);
                    pk.y = f2bf(acc[mt][nt][q * 4 + 1]);
                    pk.z = f2bf(acc[mt][nt][q * 4 + 2]);
                    pk.w = f2bf(acc[mt][nt][q * 4 + 3]);
                    *(ushort4_t*)(CF + fi) = pk;
                }
            }
        }
    if (aall) {
        const float* av = aall + (size_t)(z & amask) * 512;
        float a1v0 = av[wv * 64 + lm],       a1v1 = av[wv * 64 + 32 + lm];
        float a2v0 = av[256 + wv * 64 + lm], a2v1 = av[256 + wv * 64 + 32 + lm];
        float* sbuf = (float*)As;
#pragma unroll
        for (int mt = 0; mt < 2; ++mt)
#pragma unroll
            for (int reg = 0; reg < 16; ++reg) {
                int rl = mt * 32 + 4 * kh + (reg & 3) + 8 * (reg >> 2);
                float v1 = acc[mt][0][reg] * a1v0 + acc[mt][1][reg] * a1v1;
                float v2 = acc[mt][0][reg] * a2v0 + acc[mt][1][reg] * a2v1;
#pragma unroll
                for (int m = 1; m <= 16; m <<= 1) {
                    v1 += __shfl_xor(v1, m, 64);
                    v2 += __shfl_xor(v2, m, 64);
                }
                if (lm == 0) { sbuf[rl * 8 + wv] = v1; sbuf[rl * 8 + 4 + wv] = v2; }
            }
        __syncthreads();
        if (t < 64) {
            float s1 = sbuf[t * 8] + sbuf[t * 8 + 1] + sbuf[t * 8 + 2] + sbuf[t * 8 + 3];
            float s2 = sbuf[t * 8 + 4] + sbuf[t * 8 + 5] + sbuf[t * 8 + 6] + sbuf[t * 8 + 7];
            size_t ei = (size_t)z * Nn + m0 + t;
            E1p[ei] = __expf(s1);
            E1n[ei] = __expf(0.2f * s1);
            E2pn[ei] = make_float2(__expf(s2), __expf(0.2f * s2));
        }
    }
}

// ---------------- dual MFMA GEMM, BK=64: x1 @ [WoF ; WlF]; ng0 + fused sh scores ----------------
__global__ __launch_bounds__(256) void gemm_dual_kernel(
        const unsigned short* __restrict__ A, int K, long long sA,
        const unsigned short* __restrict__ BF,
        unsigned short* __restrict__ h2f, float* __restrict__ lin,
        const float* __restrict__ a_out,
        float* __restrict__ E1p, float* __restrict__ E1n, float2* __restrict__ E2pn) {
    int b = blockIdx.z, ng = blockIdx.y;
    A += (size_t)b * sA;
    int nfk = K >> 4;
    BF += (size_t)ng * 8 * nfk * 512;
    int m0 = blockIdx.x * 64;
    int t = threadIdx.x;
    int wv = t >> 6, lane = t & 63;
    int lm = lane & 31, kh = lane >> 5;
    __shared__ __align__(16) unsigned short As[64][72];
    f32x16 acc[2][2] = {};
    int sr = t >> 2, sc2 = (t & 3) * 16;
    const unsigned short* ag  = A + (size_t)(m0 + sr) * K + sc2;
    const unsigned short* bg0 = BF + (size_t)(wv * 2) * nfk * 512;
    const unsigned short* bg1 = bg0 + (size_t)nfk * 512;
    for (int k0 = 0; k0 < K; k0 += 64) {
        *(short8*)&As[sr][sc2]     = *(const short8*)(ag + k0);
        *(short8*)&As[sr][sc2 + 8] = *(const short8*)(ag + k0 + 8);
        int kt0 = k0 >> 4;
        __syncthreads();
#pragma unroll
        for (int s = 0; s < 4; ++s) {
            short8 a0 = *(const short8*)&As[lm][s * 16 + kh * 8];
            short8 a1 = *(const short8*)&As[32 + lm][s * 16 + kh * 8];
            short8 b0 = *(const short8*)(bg0 + (size_t)(kt0 + s) * 512 + lane * 8);
            short8 b1 = *(const short8*)(bg1 + (size_t)(kt0 + s) * 512 + lane * 8);
            acc[0][0] = __builtin_amdgcn_mfma_f32_32x32x16_bf16(a0, b0, acc[0][0], 0, 0, 0);
            acc[0][1] = __builtin_amdgcn_mfma_f32_32x32x16_bf16(a0, b1, acc[0][1], 0, 0, 0);
            acc[1][0] = __builtin_amdgcn_mfma_f32_32x32x16_bf16(a1, b0, acc[1][0], 0, 0, 0);
            acc[1][1] = __builtin_amdgcn_mfma_f32_32x32x16_bf16(a1, b1, acc[1][1], 0, 0, 0);
        }
        __syncthreads();
    }
    if (ng == 1) {
        float* C = lin + (size_t)b * Nn * 256;
#pragma unroll
        for (int mt = 0; mt < 2; ++mt)
#pragma unroll
            for (int nt = 0; nt < 2; ++nt) {
                int colg = wv * 64 + nt * 32 + lm;
#pragma unroll
                for (int reg = 0; reg < 16; ++reg) {
                    int rl = mt * 32 + 4 * kh + (reg & 3) + 8 * (reg >> 2);
                    C[(size_t)(m0 + rl) * 256 + colg] = acc[mt][nt][reg];
                }
            }
    } else {
        unsigned short* CF = h2f + (size_t)b * 524288;
#pragma unroll
        for (int mt = 0; mt < 2; ++mt)
#pragma unroll
            for (int nt = 0; nt < 2; ++nt) {
                int colg = wv * 64 + nt * 32 + lm;
#pragma unroll
                for (int q = 0; q < 4; ++q) {
                    int kt = m0 / 16 + mt * 2 + (q >> 1);
                    size_t fi = ((size_t)(colg >> 5) * 128 + kt) * 512 +
                                ((q & 1) * 32 + (colg & 31)) * 8 + kh * 4;
                    ushort4_t pk;
                    pk.x = f2bf(acc[mt][nt][q * 4 + 0]);
                    pk.y = f2bf(acc[mt][nt][q * 4 + 1]);
                    pk.z = f2bf(acc[mt][nt][q * 4 + 2]);
                    pk.w = f2bf(acc[mt][nt][q * 4 + 3]);
                    *(ushort4_t*)(CF + fi) = pk;
                }
            }
        float a1v0 = a_out[wv * 64 + lm],       a1v1 = a_out[wv * 64 + 32 + lm];
        float a2v0 = a_out[256 + wv * 64 + lm], a2v1 = a_out[256 + wv * 64 + 32 + lm];
        float* sbuf = (float*)As;
#pragma unroll
        for (int mt = 0; mt < 2; ++mt)
#pragma unroll
            for (int reg = 0; reg < 16; ++reg) {
                int rl = mt * 32 + 4 * kh + (reg & 3) + 8 * (reg >> 2);
                float v1 = acc[mt][0][reg] * a1v0 + acc[mt][1][reg] * a1v1;
                float v2 = acc[mt][0][reg] * a2v0 + acc[mt][1][reg] * a2v1;
#pragma unroll
                for (int m = 1; m <= 16; m <<= 1) {
                    v1 += __shfl_xor(v1, m, 64);
                    v2 += __shfl_xor(v2, m, 64);
                }
                if (lm == 0) { sbuf[rl * 8 + wv] = v1; sbuf[rl * 8 + 4 + wv] = v2; }
            }
        __syncthreads();
        if (t < 64) {
            float s1 = sbuf[t * 8] + sbuf[t * 8 + 1] + sbuf[t * 8 + 2] + sbuf[t * 8 + 3];
            float s2 = sbuf[t * 8 + 4] + sbuf[t * 8 + 5] + sbuf[t * 8 + 6] + sbuf[t * 8 + 7];
            size_t ei = (size_t)b * Nn + m0 + t;
            E1p[ei] = __expf(s1);
            E1n[ei] = __expf(0.2f * s1);
            E2pn[ei] = make_float2(__expf(s2), __expf(0.2f * s2));
        }
    }
}

// ---------------- pipelined MFMA attention (R11 v5 structure), frag B, max-trick ----------------
template<int JLEN, int MODE, int SWAPXY>
__global__ __launch_bounds__(256, 2) void attn_v5_kernel(
        const unsigned short* __restrict__ hfrag,
        const unsigned* __restrict__ bits,
        const float* __restrict__ E1p, const float* __restrict__ E1n,
        const float2* __restrict__ E2pn,
        unsigned short* __restrict__ outbf, int ldo,
        float* __restrict__ pacc, float* __restrict__ plsum,
        int hshift) {
    constexpr int W = JLEN / 32, NC = JLEN / 64, ABS = W + 1;
    int it = SWAPXY ? blockIdx.y : blockIdx.x;
    int bh = SWAPXY ? blockIdx.x : blockIdx.y;
    int js = blockIdx.z;
    int b = bh >> hshift, hd = bh & ((1 << hshift) - 1);
    int i0 = it * 64, jbase = js * JLEN;
    int kt0 = js * (JLEN / 16);
    int t = threadIdx.x, lane = t & 63;
    int wv = t >> 6, lm = lane & 31, kh = lane >> 5;
    int ti = lane, jq = wv;

    __shared__ unsigned ab[64 * ABS];
    __shared__ __align__(16) unsigned short ps[2][64][64];
    __shared__ float lred[64][5];
    __shared__ float linv[64];

    const unsigned* bb = bits + ((size_t)b * Nn + i0) * 64 + (jbase >> 5);
    for (int k = t; k < 64 * W; k += 256) {
        int r = k / W, w0 = k - r * W;
        ab[r * ABS + w0] = bb[(size_t)r * 64 + w0];
    }
    __syncthreads();   // ab[] must be visible before computeP

    float e1p = E1p[(size_t)bh * Nn + i0 + ti];
    float e1n = E1n[(size_t)bh * Nn + i0 + ti];
    const float4* e2base = (const float4*)(E2pn + (size_t)bh * Nn + jbase);

    const unsigned short* bg0 = hfrag + (size_t)bh * 524288 + (size_t)(wv * 2) * 128 * 512;
    const unsigned short* bg1 = bg0 + 128 * 512;

    f32x16 acc[2][2] = {};
    float lp0 = 0.f, lp1 = 0.f;   // two independent l chains
    short8 B0[8], B1[8];

    auto loadB = [&](int c, short8* B) {
#pragma unroll
        for (int s = 0; s < 4; ++s) {
            int kt = kt0 + c * 4 + s;
            B[2 * s]     = *(const short8*)(bg0 + (size_t)kt * 512 + lane * 8);
            B[2 * s + 1] = *(const short8*)(bg1 + (size_t)kt * 512 + lane * 8);
        }
    };
    auto computeP = [&](int c, int buf) {
        int cj = c * 64;
        unsigned word = ab[ti * ABS + ((cj >> 5) + (jq >> 1))];
        unsigned field = word >> ((jq & 1) * 16);
        const float4* ep = e2base + ((cj + jq * 16) >> 1);
        unsigned pk[8];
#pragma unroll
        for (int u = 0; u < 8; ++u) {
            float4 q = ep[u];
            // exp(s)>exp(0.2s) iff s>0  =>  select == max (exact)
            float p0 = fmaxf(e1p * q.x, e1n * q.y);
            p0 = ((field >> (2 * u)) & 1u) ? p0 : 0.f;
            float p1 = fmaxf(e1p * q.z, e1n * q.w);
            p1 = ((field >> (2 * u + 1)) & 1u) ? p1 : 0.f;
            if (u & 1) lp1 += p0 + p1; else lp0 += p0 + p1;
            __hip_bfloat162 hv = __float22bfloat162_rn(make_float2(p0, p1));
            pk[u] = *(unsigned*)&hv;
        }
        unsigned sw = ti & 7;
        uint4 v0; v0.x = pk[0]; v0.y = pk[1]; v0.z = pk[2]; v0.w = pk[3];
        uint4 v1; v1.x = pk[4]; v1.y = pk[5]; v1.z = pk[6]; v1.w = pk[7];
        *(uint4*)&ps[buf][ti][((2 * jq) ^ sw) * 8]     = v0;
        *(uint4*)&ps[buf][ti][((2 * jq + 1) ^ sw) * 8] = v1;
    };
    auto mfmaStep = [&](int buf, short8* B) {
        unsigned sw = lm & 7;
#pragma unroll
        for (int s = 0; s < 4; ++s) {
            short8 a0 = *(const short8*)&ps[buf][lm][((2 * s + kh) ^ sw) * 8];
            short8 a1 = *(const short8*)&ps[buf][32 + lm][((2 * s + kh) ^ sw) * 8];
            acc[0][0] = __builtin_amdgcn_mfma_f32_32x32x16_bf16(a0, B[2 * s],     acc[0][0], 0, 0, 0);
            acc[0][1] = __builtin_amdgcn_mfma_f32_32x32x16_bf16(a0, B[2 * s + 1], acc[0][1], 0, 0, 0);
            acc[1][0] = __builtin_amdgcn_mfma_f32_32x32x16_bf16(a1, B[2 * s],     acc[1][0], 0, 0, 0);
            acc[1][1] = __builtin_amdgcn_mfma_f32_32x32x16_bf16(a1, B[2 * s + 1], acc[1][1], 0, 0, 0);
        }
    };

    loadB(0, B0);
    computeP(0, 0);
    __syncthreads();
    for (int c = 0; c < NC; c += 2) {
        loadB(c + 1, B1);
        mfmaStep(0, B0);
        computeP(c + 1, 1);
        __syncthreads();
        if (c + 2 < NC) loadB(c + 2, B0);
        mfmaStep(1, B1);
        if (c + 2 < NC) computeP(c + 2, 0);
        __syncthreads();
    }

    lred[ti][jq] = lp0 + lp1;
    __syncthreads();
    if (MODE == 0) {
        if (t < 64) linv[t] = 1.f / (lred[t][0] + lred[t][1] + lred[t][2] + lred[t][3]);
        __syncthreads();
#pragma unroll
        for (int mt = 0; mt < 2; ++mt)
#pragma unroll
            for (int nt = 0; nt < 2; ++nt) {
                int o = wv * 64 + nt * 32 + lm;
#pragma unroll
                for (int reg = 0; reg < 16; ++reg) {
                    int rl = mt * 32 + 4 * kh + (reg & 3) + 8 * (reg >> 2);
                    float v = acc[mt][nt][reg] * linv[rl];
                    v = v > 0.f ? v : expm1f(v);   // elu (layer 1)
                    outbf[((size_t)b * Nn + i0 + rl) * ldo + (size_t)hd * Oo + o] = f2bf(v);
                }
            }
    } else {
        if (t < 64)
            plsum[((size_t)js * Bb + b) * Nn + i0 + t] =
                lred[t][0] + lred[t][1] + lred[t][2] + lred[t][3];
        float* pa = pacc + (((size_t)js * Bb + b) * Nn) * 256;
#pragma unroll
        for (int mt = 0; mt < 2; ++mt)
#pragma unroll
            for (int nt = 0; nt < 2; ++nt) {
                int o = wv * 64 + nt * 32 + lm;
#pragma unroll
                for (int reg = 0; reg < 16; ++reg) {
                    int rl = mt * 32 + 4 * kh + (reg & 3) + 8 * (reg >> 2);
                    pa[(size_t)(i0 + rl) * 256 + o] = acc[mt][nt][reg];
                }
            }
    }
}

// ---------------- combine 8 partials: x2 = Σacc/Σl + lin + b ----------------
__global__ __launch_bounds__(256) void combine8_kernel(
        const float* __restrict__ pacc, const float* __restrict__ plsum,
        const float* __restrict__ lin, const float* __restrict__ bias,
        unsigned short* __restrict__ out) {
    int gid = blockIdx.x * 256 + threadIdx.x;
    int row = gid >> 6;
    int o4 = gid & 63;
    size_t ps4 = (size_t)Bb * Nn * 64;
    const float4* p = (const float4*)pacc + (size_t)row * 64 + o4;
    float4 s = p[0];
#pragma unroll
    for (int k = 1; k < 8; ++k) {
        float4 q = p[k * ps4];
        s.x += q.x; s.y += q.y; s.z += q.z; s.w += q.w;
    }
    int BN = Bb * Nn;
    float lsum = 0.f;
#pragma unroll
    for (int k = 0; k < 8; ++k) lsum += plsum[row + k * BN];
    float li = 1.f / lsum;
    float4 lv = ((const float4*)lin)[(size_t)row * 64 + o4];
    float4 bv = ((const float4*)bias)[o4];
    float4 v;
    v.x = s.x * li + lv.x + bv.x; v.y = s.y * li + lv.y + bv.y;
    v.z = s.z * li + lv.z + bv.z; v.w = s.w * li + lv.w + bv.w;
    __hip_bfloat162 h0 = __float22bfloat162_rn(make_float2(v.x, v.y));
    __hip_bfloat162 h1 = __float22bfloat162_rn(make_float2(v.z, v.w));
    uint2 st; st.x = *(unsigned*)&h0; st.y = *(unsigned*)&h1;
    *(uint2*)(out + (size_t)gid * 4) = st;
}

extern "C" void kernel_launch(void* const* d_in, const int* in_sizes, int n_in,
                              void* d_out, int out_size, void* d_ws, size_t ws_size,
                              hipStream_t stream) {
    const float* x       = (const float*)d_in[0];
    const float* adj     = (const float*)d_in[1];
    const float* W_heads = (const float*)d_in[3];
    const float* a_heads = (const float*)d_in[4];
    const float* W_out   = (const float*)d_in[5];
    const float* a_out   = (const float*)d_in[6];
    const float* W_lin   = (const float*)d_in[7];
    const float* b_lin   = (const float*)d_in[8];
    const float* W_ln    = (const float*)d_in[9];
    const float* b_ln    = (const float*)d_in[10];

    char* w = (char*)d_ws;
    float* pacc     = (float*)(w);                    // 8x4 MB (sh partials)
    float* lin      = (float*)(w + 33554432);
    float* E1p_mh   = (float*)(w + 41943040);
    float* E1n_mh   = (float*)(w + 42074112);
    float2* E2pn_mh = (float2*)(w + 42205184);
    float* E1p_sh   = (float*)(w + 42467328);
    float* E1n_sh   = (float*)(w + 42483712);
    float2* E2pn_sh = (float2*)(w + 42500096);
    unsigned long long* bits = (unsigned long long*)(w + 42532864);
    unsigned short* x_bf  = (unsigned short*)(w + 43581440);
    unsigned short* x2_bf = (unsigned short*)(w + 43581440);   // reuse after gemm1
    unsigned short* WhF   = (unsigned short*)(w + 49872896);
    unsigned short* WoF   = (unsigned short*)(w + 53018624);
    unsigned short* WlF   = (unsigned short*)(w + 54067200);
    unsigned short* WnF   = (unsigned short*)(w + 55115776);
    unsigned short* hfrag = (unsigned short*)(w + 55246848);   // 16 MB
    unsigned short* h2frag= (unsigned short*)(w + 72024064);   // 2 MB
    unsigned short* x1_bf = (unsigned short*)(w + 74121216);
    float* plsum = E1p_mh;

    // 0) prep
    adjbits_kernel<<<(Bb * Nn * Nn) / 256, 256, 0, stream>>>(adj, bits);
    cast_bf_kernel<<<(Bb * Nn * Ff) / 1024, 256, 0, stream>>>(x, x_bf);
    wfrag_kn_kernel<<<dim3(96, Hh), 256, 0, stream>>>(
        W_heads, WhF, Ff, Oo, (long long)Ff * Oo, 384LL * 512);
    wfrag_kn_kernel<<<dim3(256, 1), 256, 0, stream>>>(
        W_out, WoF, Hh * Oo, Oo, 0, 0);
    wfrag_nk_kernel<<<256, 256, 0, stream>>>(W_lin, WlF, Hh * Oo);
    wfrag_nk_kernel<<<32, 256, 0, stream>>>(W_ln, WnF, Oo);

    // 1) h = x @ W_heads -> hfrag + fused mh scores/exp
    gemm_bf_kernel<<<dim3(Nn / 64, 1, Bb * Hh), 256, 0, stream>>>(
        x_bf, Ff, (long long)Nn * Ff, 3, WhF, 384LL * 512, 7,
        nullptr, 0, hfrag, 524288, Nn, nullptr, 1,
        a_heads, 7, E1p_mh, E1n_mh, E2pn_mh);
    // 2) multihead attention + elu -> x1_bf  (bh-major grid: XCD = bh%8)
    attn_v5_kernel<2048, 0, 1><<<dim3(Bb * Hh, Nn / 64, 1), 256, 0, stream>>>(
        hfrag, (const unsigned*)bits, E1p_mh, E1n_mh, E2pn_mh,
        x1_bf, Hh * Oo, nullptr, nullptr, 3);
    // 3) fused dual GEMM: h2frag (+sh scores) and lin
    gemm_dual_kernel<<<dim3(Nn / 64, 2, Bb), 256, 0, stream>>>(
        x1_bf, Hh * Oo, (long long)Nn * Hh * Oo, WoF, h2frag, lin,
        a_out, E1p_sh, E1n_sh, E2pn_sh);
    // 4) single-head attention, 8-way j-split partials
    attn_v5_kernel<256, 1, 0><<<dim3(Nn / 64, Bb, 8), 256, 0, stream>>>(
        h2frag, (const unsigned*)bits, E1p_sh, E1n_sh, E2pn_sh,
        nullptr, 0, pacc, plsum, 0);
    // 5) combine -> x2_bf
    combine8_kernel<<<(Bb * Nn * 64) / 256, 256, 0, stream>>>(pacc, plsum, lin, b_lin, x2_bf);
    // 6) out = relu(x2 @ W_ln^T + b_ln)
    gemm_bf_kernel<<<dim3(Nn / 64, 1, Bb), 256, 0, stream>>>(
        x2_bf, Oo, (long long)Nn * Oo, 0, WnF, 0, 0,
        (float*)d_out, (long long)Nn * Oo, nullptr, 0, Nn, b_ln, 2,
        nullptr, 0, nullptr, nullptr, nullptr);
}